// Round 14
// baseline (340.084 us; speedup 1.0000x reference)
//
#include <hip/hip_runtime.h>
#include <stdint.h>

#define PRIME 2013265921u
#define LOGN 21
#define NN (1u << LOGN)   // 2097152

// ---------- compile-time modular helpers ----------
constexpr uint32_t cpow(uint64_t b, uint64_t e) {
    uint64_t r = 1;
    b %= PRIME;
    while (e) {
        if (e & 1ull) r = r * b % PRIME;
        b = b * b % PRIME;
        e >>= 1;
    }
    return (uint32_t)r;
}
constexpr uint32_t cpinv() {           // PRIME^{-1} mod 2^32 (Newton)
    uint32_t inv = 1;
    for (int i = 0; i < 6; i++) inv *= 2u - PRIME * inv;
    return inv;
}
constexpr uint32_t NPRIME   = (uint32_t)(0u - cpinv());            // -P^{-1} mod 2^32
constexpr uint32_t RMODP    = (uint32_t)((1ull << 32) % PRIME);    // Mont(1)
constexpr uint32_t ROOT     = cpow(31u, (PRIME - 1) / NN);
constexpr uint32_t IROOT    = cpow(ROOT, PRIME - 2);
constexpr uint32_t NINV     = cpow(NN, PRIME - 2);
constexpr uint32_t NINV_M   = (uint32_t)((((uint64_t)NINV) << 32) % PRIME);  // Mont(N^-1)

// ---------- modular arithmetic ----------
__device__ __forceinline__ uint32_t addmod(uint32_t a, uint32_t b) {
    uint32_t s = a + b; return (s >= PRIME) ? s - PRIME : s;
}
__device__ __forceinline__ uint32_t submod(uint32_t a, uint32_t b) {
    return (a >= b) ? (a - b) : (a + PRIME - b);
}
__device__ __forceinline__ uint32_t mulmod(uint32_t a, uint32_t b) {
    return (uint32_t)(((uint64_t)a * (uint64_t)b) % PRIME);
}
// Montgomery: montmul(a_normal, Mont(b)) = a*b mod P; montmul(Mont(a),Mont(b)) = Mont(ab)
__device__ __forceinline__ uint32_t montmul(uint32_t a, uint32_t b) {
    uint64_t t = (uint64_t)a * b;
    uint32_t m = (uint32_t)t * NPRIME;
    uint32_t u = (uint32_t)((t + (uint64_t)m * PRIME) >> 32);
    return (u >= PRIME) ? u - PRIME : u;
}
__device__ uint32_t powmod(uint32_t b, uint32_t e) {
    uint32_t r = 1u;
    while (e) {
        if (e & 1u) r = mulmod(r, b);
        b = mulmod(b, b);
        e >>= 1;
    }
    return r;
}
__device__ __forceinline__ uint32_t tomont(uint32_t x) {
    return (uint32_t)((((uint64_t)x) << 32) % PRIME);
}

// ---------- twiddle tables (single dispatch, direct powmod) ----------
//   WT1[idx]  (idx<4096)  : WT1[2^s+j] = Mont(iroot^(j<<(20-s)))      (phase1 stage-packed)
//   ROWT[i]   (i<512)     : ROWT[2^t+kk] = Mont(iroot^(kk<<(20-t)))   (phase2 row factors)
//   CW[s*4096+j] (s<9)    : Mont(iroot^(j<<(8-s)))                     (phase2 col factors)
__global__ void twiddle_all_kernel(uint32_t* __restrict__ WT1, uint32_t* __restrict__ ROWT,
                                   uint32_t* __restrict__ CW) {
    uint32_t i = blockIdx.x * blockDim.x + threadIdx.x;   // < 36864
    if (i < 4096) {
        if (i == 0) WT1[0] = RMODP;
        else {
            uint32_t s = 31u - __clz(i);
            uint32_t j = i ^ (1u << s);
            WT1[i] = tomont(powmod(IROOT, j << (20u - s)));
        }
    }
    if (i < 512) {
        if (i == 0) ROWT[0] = RMODP;
        else {
            uint32_t t = 31u - __clz(i);
            ROWT[i] = tomont(powmod(IROOT, (i - (1u << t)) << (20u - t)));
        }
    }
    if (i < 36864) {
        uint32_t s = i >> 12, j = i & 4095u;
        CW[i] = tomont(powmod(IROOT, j << (8u - s)));
    }
}

// ---------- compress (int4 vectorized) + fused coarse (64-bucket) histogram ----------
__global__ __launch_bounds__(256) void compress_kernel(
        const int* __restrict__ wl, const int* __restrict__ wr,
        const int* __restrict__ wo, const int* __restrict__ w4,
        const int* __restrict__ t1, const int* __restrict__ t2,
        const int* __restrict__ t3, const int* __restrict__ t4,
        const int* __restrict__ q,  const int* __restrict__ zp,
        uint32_t* __restrict__ tcomp, uint32_t* __restrict__ fcomp,
        unsigned int* __restrict__ hist64) {
    __shared__ unsigned int h64[64];
    if (threadIdx.x < 64) h64[threadIdx.x] = 0;
    __syncthreads();
    uint32_t z1 = ((uint32_t)zp[0]) % PRIME;
    uint32_t z2 = mulmod(z1, z1);
    uint32_t z3 = mulmod(z2, z1);
    uint32_t i0 = (blockIdx.x * 256u + threadIdx.x) * 4u;   // grid 2048 covers NN exactly
    int4 a1 = *reinterpret_cast<const int4*>(&t1[i0]);
    int4 a2 = *reinterpret_cast<const int4*>(&t2[i0]);
    int4 a3 = *reinterpret_cast<const int4*>(&t3[i0]);
    int4 a4 = *reinterpret_cast<const int4*>(&t4[i0]);
    int4 b1 = *reinterpret_cast<const int4*>(&wl[i0]);
    int4 b2 = *reinterpret_cast<const int4*>(&wr[i0]);
    int4 b3 = *reinterpret_cast<const int4*>(&wo[i0]);
    int4 b4 = *reinterpret_cast<const int4*>(&w4[i0]);
    int4 qq = *reinterpret_cast<const int4*>(&q[i0]);
    uint4 tv, fv;
    {
        uint32_t t = addmod(addmod((uint32_t)a1.x, mulmod((uint32_t)a2.x, z1)),
                            addmod(mulmod((uint32_t)a3.x, z2), mulmod((uint32_t)a4.x, z3)));
        uint32_t w = addmod(addmod((uint32_t)b1.x, mulmod((uint32_t)b2.x, z1)),
                            addmod(mulmod((uint32_t)b3.x, z2), mulmod((uint32_t)b4.x, z3)));
        tv.x = t; fv.x = (qq.x != 0) ? w : t;
    }
    {
        uint32_t t = addmod(addmod((uint32_t)a1.y, mulmod((uint32_t)a2.y, z1)),
                            addmod(mulmod((uint32_t)a3.y, z2), mulmod((uint32_t)a4.y, z3)));
        uint32_t w = addmod(addmod((uint32_t)b1.y, mulmod((uint32_t)b2.y, z1)),
                            addmod(mulmod((uint32_t)b3.y, z2), mulmod((uint32_t)b4.y, z3)));
        tv.y = t; fv.y = (qq.y != 0) ? w : t;
    }
    {
        uint32_t t = addmod(addmod((uint32_t)a1.z, mulmod((uint32_t)a2.z, z1)),
                            addmod(mulmod((uint32_t)a3.z, z2), mulmod((uint32_t)a4.z, z3)));
        uint32_t w = addmod(addmod((uint32_t)b1.z, mulmod((uint32_t)b2.z, z1)),
                            addmod(mulmod((uint32_t)b3.z, z2), mulmod((uint32_t)b4.z, z3)));
        tv.z = t; fv.z = (qq.z != 0) ? w : t;
    }
    {
        uint32_t t = addmod(addmod((uint32_t)a1.w, mulmod((uint32_t)a2.w, z1)),
                            addmod(mulmod((uint32_t)a3.w, z2), mulmod((uint32_t)a4.w, z3)));
        uint32_t w = addmod(addmod((uint32_t)b1.w, mulmod((uint32_t)b2.w, z1)),
                            addmod(mulmod((uint32_t)b3.w, z2), mulmod((uint32_t)b4.w, z3)));
        tv.w = t; fv.w = (qq.w != 0) ? w : t;
    }
    *reinterpret_cast<uint4*>(&tcomp[i0]) = tv;
    *reinterpret_cast<uint4*>(&fcomp[i0]) = fv;
    atomicAdd(&h64[tv.x >> 25], 1u); atomicAdd(&h64[fv.x >> 25], 1u);
    atomicAdd(&h64[tv.y >> 25], 1u); atomicAdd(&h64[fv.y >> 25], 1u);
    atomicAdd(&h64[tv.z >> 25], 1u); atomicAdd(&h64[fv.z >> 25], 1u);
    atomicAdd(&h64[tv.w >> 25], 1u); atomicAdd(&h64[fv.w >> 25], 1u);
    __syncthreads();
    if (threadIdx.x < 64 && h64[threadIdx.x])
        atomicAdd(&hist64[threadIdx.x], h64[threadIdx.x]);
}

// ---------- sort ----------
#define NBUCK 8192

__global__ void scan64_kernel(const unsigned int* __restrict__ hist64,
                              unsigned int* __restrict__ cbase, unsigned int* __restrict__ ccursor) {
    if (threadIdx.x == 0) {
        unsigned int run = 0;
        for (int b = 0; b < 64; b++) { cbase[b] = run; ccursor[b] = run; run += hist64[b]; }
        cbase[64] = run;
    }
}

// pass 1: scatter into 64 coarse buckets with LDS grouping (uint4 loads)
__global__ __launch_bounds__(256) void pass1_kernel(const uint32_t* __restrict__ tcomp,
                                                    const uint32_t* __restrict__ fcomp,
                                                    unsigned int* __restrict__ ccursor,
                                                    uint32_t* __restrict__ barr1) {
    __shared__ uint32_t grp[4096];
    __shared__ unsigned char grpb[4096];
    __shared__ unsigned int cnt[64], pref[64], curs[64], rbase[64];
    uint32_t tid = threadIdx.x;
    const uint32_t* srcp = (blockIdx.x < 512) ? (tcomp + blockIdx.x * 4096)
                                              : (fcomp + (blockIdx.x - 512) * 4096);
    if (tid < 64) cnt[tid] = 0;
    __syncthreads();
    uint4 vv[4];
    #pragma unroll
    for (uint32_t m = 0; m < 4; m++) {
        uint32_t l = (m * 256u + tid) * 4u;
        vv[m] = *reinterpret_cast<const uint4*>(&srcp[l]);
        atomicAdd(&cnt[vv[m].x >> 25], 1u);
        atomicAdd(&cnt[vv[m].y >> 25], 1u);
        atomicAdd(&cnt[vv[m].z >> 25], 1u);
        atomicAdd(&cnt[vv[m].w >> 25], 1u);
    }
    __syncthreads();
    if (tid == 0) {
        unsigned int run = 0;
        for (int b = 0; b < 64; b++) { pref[b] = run; curs[b] = run; run += cnt[b]; }
    }
    __syncthreads();
    if (tid < 64 && cnt[tid]) rbase[tid] = atomicAdd(&ccursor[tid], cnt[tid]);
    #pragma unroll
    for (uint32_t m = 0; m < 4; m++) {
        uint32_t vs[4] = {vv[m].x, vv[m].y, vv[m].z, vv[m].w};
        #pragma unroll
        for (int j = 0; j < 4; j++) {
            uint32_t v = vs[j];
            uint32_t b = v >> 25;
            unsigned int p = atomicAdd(&curs[b], 1u);
            grp[p] = v; grpb[p] = (unsigned char)b;
        }
    }
    __syncthreads();
    for (uint32_t l = tid; l < 4096; l += 256) {
        uint32_t b = grpb[l];
        barr1[rbase[b] + (l - pref[b])] = grp[l];
    }
}

// fine (8192-bucket) histogram from coarse-partitioned data
__global__ __launch_bounds__(256) void fine_hist_kernel(const uint32_t* __restrict__ barr1,
                                                        const unsigned int* __restrict__ cbase,
                                                        unsigned int* __restrict__ hist) {
    __shared__ unsigned int cnt[128];
    uint32_t tid = threadIdx.x;
    uint32_t reg = blockIdx.y;
    if (tid < 128) cnt[tid] = 0;
    __syncthreads();
    uint32_t lo = cbase[reg], hi = cbase[reg + 1];
    for (uint32_t i = lo + blockIdx.x * 256 + tid; i < hi; i += gridDim.x * 256)
        atomicAdd(&cnt[(barr1[i] >> 18) & 127u], 1u);
    __syncthreads();
    if (tid < 128 && cnt[tid]) atomicAdd(&hist[reg * 128 + tid], cnt[tid]);
}

__global__ void scan_kernel(const unsigned int* __restrict__ hist,
                            unsigned int* __restrict__ basearr, unsigned int* __restrict__ fcursor) {
    __shared__ unsigned int ls[256];
    int t = threadIdx.x;
    unsigned int local[32];
    unsigned int s = 0;
    for (int k = 0; k < 32; k++) { local[k] = hist[t * 32 + k]; s += local[k]; }
    ls[t] = s;
    __syncthreads();
    for (int off = 1; off < 256; off <<= 1) {
        unsigned int v = (t >= off) ? ls[t - off] : 0u;
        __syncthreads();
        ls[t] += v;
        __syncthreads();
    }
    unsigned int run = ls[t] - s;  // exclusive prefix
    for (int k = 0; k < 32; k++) {
        basearr[t * 32 + k] = run;
        fcursor[t * 32 + k] = run;
        run += local[k];
    }
    if (t == 255) basearr[NBUCK] = run;
}

// pass 2: within each coarse region, scatter into 128 fine buckets (LDS grouping)
__global__ __launch_bounds__(256) void pass2_kernel(const uint32_t* __restrict__ barr1,
                                                    const unsigned int* __restrict__ cbase,
                                                    unsigned int* __restrict__ fcursor,
                                                    uint32_t* __restrict__ barr2) {
    __shared__ uint32_t grp[4096];
    __shared__ unsigned char grpb[4096];
    __shared__ unsigned int cnt[128], pref[128], curs[128], rbase[128];
    uint32_t tid = threadIdx.x;
    uint32_t reg = blockIdx.y;
    uint32_t lo = cbase[reg], hi = cbase[reg + 1];
    for (uint32_t start = lo + blockIdx.x * 4096; start < hi; start += gridDim.x * 4096) {
        uint32_t n = min(4096u, hi - start);
        if (tid < 128) cnt[tid] = 0;
        __syncthreads();
        for (uint32_t l = tid; l < n; l += 256)
            atomicAdd(&cnt[(barr1[start + l] >> 18) & 127u], 1u);
        __syncthreads();
        if (tid == 0) {
            unsigned int run = 0;
            for (int b = 0; b < 128; b++) { pref[b] = run; curs[b] = run; run += cnt[b]; }
        }
        __syncthreads();
        if (tid < 128 && cnt[tid]) rbase[tid] = atomicAdd(&fcursor[reg * 128 + tid], cnt[tid]);
        for (uint32_t l = tid; l < n; l += 256) {
            uint32_t v = barr1[start + l];
            uint32_t b = (v >> 18) & 127u;
            unsigned int p = atomicAdd(&curs[b], 1u);
            grp[p] = v; grpb[p] = (unsigned char)b;
        }
        __syncthreads();
        for (uint32_t l = tid; l < n; l += 256) {
            uint32_t b = grpb[l];
            barr2[rbase[b] + (l - pref[b])] = grp[l];
        }
        __syncthreads();
    }
}

// ---------- per-bucket O(n) MSD counting sort (256 sub-bins, bits 17:10) ----------
__global__ __launch_bounds__(256) void bucket_sort_kernel(const uint32_t* __restrict__ barr,
                                                          const unsigned int* __restrict__ basearr,
                                                          uint32_t* __restrict__ h1, uint32_t* __restrict__ h2) {
    __shared__ uint32_t ord[4096];
    __shared__ unsigned int cnt[256], pref[256], curs[256];
    uint32_t b  = blockIdx.x;
    uint32_t lo = basearr[b], hi = basearr[b + 1];
    uint32_t n  = hi - lo;
    if (n == 0) return;
    if (n > 4096) n = 4096;   // unreachable for this distribution
    uint32_t tid = threadIdx.x;
    cnt[tid] = 0;
    __syncthreads();
    for (uint32_t i = tid; i < n; i += 256)
        atomicAdd(&cnt[(barr[lo + i] >> 10) & 255u], 1u);
    __syncthreads();
    if (tid == 0) {
        unsigned int run = 0;
        for (int d = 0; d < 256; d++) { pref[d] = run; curs[d] = run; run += cnt[d]; }
    }
    __syncthreads();
    for (uint32_t i = tid; i < n; i += 256) {
        uint32_t v = barr[lo + i];
        uint32_t d = (v >> 10) & 255u;
        unsigned int p = atomicAdd(&curs[d], 1u);
        ord[p] = v;
    }
    __syncthreads();
    for (uint32_t p = tid; p < n; p += 256) {
        uint32_t v = ord[p];
        uint32_t d = (v >> 10) & 255u;
        uint32_t l0 = pref[d], l1 = l0 + cnt[d];
        uint32_t r = 0;
        for (uint32_t qq = l0; qq < l1; qq++) {
            uint32_t u = ord[qq];
            r += (u < v) || (u == v && qq < p);
        }
        uint32_t gp = lo + l0 + r;
        if (gp & 1) h2[gp >> 1] = v; else h1[gp >> 1] = v;
    }
}

// ---------- NTT stages 1..12 with FUSED bit-reversal gather; radix-4 (6 rounds) ----------
// Block (poly, chunk=rev9(r)) loads sd[rev12(m)] = src[m*512 + r] directly (no bitrev pass).
// XCD mapping gives each XCD a window of consecutive r per poly -> every 64B line of the
// stride-2KB gather is shared ~16x through that XCD's L2 (window footprint 2MB < 4MB L2).
// w2j trick: W_{s+1}[j]*J = W_{s+1}[j+h] -> wt[3h+j], no montmul.
struct SrcPtrs { const uint32_t* p[8]; };

__device__ __forceinline__ uint32_t padi(uint32_t i) { return i + (i >> 5); }

__global__ __launch_bounds__(256) void ntt_phase1_kernel(SrcPtrs srcs, uint32_t* __restrict__ polys,
                                                         const uint32_t* __restrict__ WT1) {
    __shared__ uint32_t wt[4096];
    __shared__ uint32_t sd[4224];     // padded: i + (i>>5)
    uint32_t bb = blockIdx.x;             // 0..4095
    uint32_t xcd = bb & 7u, k = bb >> 3;  // k: 0..511
    uint32_t poly = k >> 6;               // 0..7
    uint32_t r = xcd * 64u + (k & 63u);   // 0..511 (consecutive per XCD per poly)
    uint32_t chunk = __brev(r) >> 23;     // rev9
    const uint32_t* src = srcs.p[poly];
    uint32_t* x = polys + (size_t)poly * NN + (size_t)chunk * 4096;
    uint32_t tid = threadIdx.x;

    // twiddle preload (uint4, contiguous)
    #pragma unroll
    for (uint32_t m = 0; m < 4; m++) {
        uint32_t l = m * 1024 + tid * 4;
        *reinterpret_cast<uint4*>(&wt[l]) = *reinterpret_cast<const uint4*>(&WT1[l]);
    }
    // fused bitrev gather: sd[padi(rev12(m))] = src[m*512 + r]
    #pragma unroll
    for (uint32_t it = 0; it < 16; it++) {
        uint32_t m = tid + it * 256u;
        sd[padi(__brev(m) >> 20)] = src[m * 512u + r];
    }
    __syncthreads();

    // 6 radix-4 rounds = stage pairs (1,2),(3,4),...,(11,12)
    #pragma unroll
    for (int t = 0; t < 6; t++) {
        uint32_t h = 1u << (2 * t);
        #pragma unroll
        for (uint32_t m = 0; m < 4; m++) {
            uint32_t q = tid + (m << 8);     // unit 0..1023
            uint32_t j = q & (h - 1);
            uint32_t grp = q >> (2 * t);
            uint32_t i0 = (grp << (2 * t + 2)) + j;
            uint32_t w1  = wt[h + j];
            uint32_t w2  = wt[2 * h + j];
            uint32_t w2j = wt[3 * h + j];
            uint32_t p0 = padi(i0), p1 = padi(i0 + h), p2 = padi(i0 + 2 * h), p3 = padi(i0 + 3 * h);
            uint32_t a0 = sd[p0], a1 = sd[p1], a2 = sd[p2], a3 = sd[p3];
            uint32_t t1 = montmul(w1, a1), t3 = montmul(w1, a3);
            uint32_t b0 = addmod(a0, t1), b1 = submod(a0, t1);
            uint32_t b2 = addmod(a2, t3), b3 = submod(a2, t3);
            uint32_t u2 = montmul(w2, b2), u3 = montmul(w2j, b3);
            sd[p0] = addmod(b0, u2);
            sd[p2] = submod(b0, u2);
            sd[p1] = addmod(b1, u3);
            sd[p3] = submod(b1, u3);
        }
        __syncthreads();
    }
    // fold in N^-1 scaling; vectorized store (contiguous 16KB per block)
    #pragma unroll
    for (uint32_t m = 0; m < 4; m++) {
        uint32_t l = m * 1024 + tid * 4;
        uint32_t p = padi(l);
        uint4 v;
        v.x = montmul(sd[p], NINV_M);
        v.y = montmul(sd[p + 1], NINV_M);
        v.z = montmul(sd[p + 2], NINV_M);
        v.w = montmul(sd[p + 3], NINV_M);
        *reinterpret_cast<uint4*>(&x[l]) = v;
    }
}

// ---------- NTT stages 13..21: 32-col x 512-row tile (64KB LDS, conflict-free);
//            uint4/float4 global I/O; radix-4 x4 + radix-2; fused commit; XCD remap ----------
__global__ __launch_bounds__(512) void ntt_phase2_kernel(uint32_t* __restrict__ polys,
                                                         const uint32_t* __restrict__ ROWT,
                                                         const uint32_t* __restrict__ CW,
                                                         const float* __restrict__ g,
                                                         double* __restrict__ partials) {
    __shared__ __align__(16) uint32_t sd[16384];    // [row:512][col:32] — 64 KB, banks ≡ col
    uint32_t b = blockIdx.x;              // 0..1023
    uint32_t xcd = b & 7u, k = b >> 3;    // k: 0..127
    uint32_t poly = k >> 4;               // 0..7
    uint32_t c0_idx = xcd * 16u + (k & 15u);   // 0..127
    uint32_t* x = polys + (size_t)poly * NN;
    uint32_t c0 = c0_idx * 32u;
    uint32_t tid = threadIdx.x;           // 0..511
    uint32_t c = tid & 31u;
    uint32_t rt = tid >> 5;               // 0..15
    uint32_t cg = tid & 7u;               // col group (4 cols)
    uint32_t r0 = tid >> 3;               // 0..63

    #pragma unroll
    for (uint32_t kk = 0; kk < 8; kk++) {
        uint32_t row = r0 + kk * 64;
        uint4 v = *reinterpret_cast<const uint4*>(&x[(row << 12) + c0 + 4 * cg]);
        *reinterpret_cast<uint4*>(&sd[row * 32 + 4 * cg]) = v;
    }
    uint32_t cw[9];
    #pragma unroll
    for (int s = 0; s < 9; s++) cw[s] = CW[s * 4096 + c0 + c];
    __syncthreads();

    #pragma unroll
    for (int s = 0; s < 8; s += 2) {
        uint32_t h = 1u << s;
        #pragma unroll
        for (uint32_t m = 0; m < 8; m++) {
            uint32_t u = (rt << 3) + m;          // radix-4 unit 0..127
            uint32_t kk = u & (h - 1);
            uint32_t grp = u >> s;
            uint32_t r = (grp << (s + 2)) + kk;
            uint32_t w1  = montmul(ROWT[h + kk], cw[s]);
            uint32_t w2  = montmul(ROWT[2 * h + kk], cw[s + 1]);
            uint32_t w2j = montmul(ROWT[3 * h + kk], cw[s + 1]);
            uint32_t i0 = (r << 5) + c;
            uint32_t i1 = ((r + h) << 5) + c;
            uint32_t i2 = ((r + 2 * h) << 5) + c;
            uint32_t i3 = ((r + 3 * h) << 5) + c;
            uint32_t a0 = sd[i0], a1 = sd[i1], a2 = sd[i2], a3 = sd[i3];
            uint32_t t1 = montmul(w1, a1), t3 = montmul(w1, a3);
            uint32_t b0 = addmod(a0, t1), b1 = submod(a0, t1);
            uint32_t b2 = addmod(a2, t3), b3 = submod(a2, t3);
            uint32_t u2 = montmul(w2, b2), u3 = montmul(w2j, b3);
            sd[i0] = addmod(b0, u2);
            sd[i2] = submod(b0, u2);
            sd[i1] = addmod(b1, u3);
            sd[i3] = submod(b1, u3);
        }
        __syncthreads();
    }
    #pragma unroll
    for (uint32_t m = 0; m < 16; m++) {
        uint32_t kk = (rt << 4) + m;       // 0..255
        uint32_t w = montmul(ROWT[256 + kk], cw[8]);
        uint32_t i0 = (kk << 5) + c, i1 = ((kk + 256) << 5) + c;
        uint32_t u = sd[i0];
        uint32_t v = montmul(sd[i1], w);
        sd[i0] = addmod(u, v);
        sd[i1] = submod(u, v);
    }
    __syncthreads();

    float* xf = (float*)x;
    const float invp = (float)(1.0 / 2013265921.0);
    double a0 = 0.0, a1 = 0.0, a2 = 0.0;
    #pragma unroll
    for (uint32_t kk = 0; kk < 8; kk++) {
        uint32_t row = r0 + kk * 64;
        uint32_t idx0 = (row << 12) + c0 + 4 * cg;
        uint32_t base = row * 32 + 4 * cg;
        float f0 = (float)sd[base], f1 = (float)sd[base + 1];
        float f2 = (float)sd[base + 2], f3 = (float)sd[base + 3];
        float4 fv = make_float4(f0, f1, f2, f3);
        *reinterpret_cast<float4*>(&xf[idx0]) = fv;
        const float4* gp = reinterpret_cast<const float4*>(&g[(size_t)idx0 * 3]);
        float4 g0 = gp[0], g1 = gp[1], g2 = gp[2];
        float s0 = f0 * invp, s1 = f1 * invp, s2 = f2 * invp, s3 = f3 * invp;
        a0 += (double)(s0 * g0.x) + (double)(s1 * g0.w) + (double)(s2 * g1.z) + (double)(s3 * g2.y);
        a1 += (double)(s0 * g0.y) + (double)(s1 * g1.x) + (double)(s2 * g1.w) + (double)(s3 * g2.z);
        a2 += (double)(s0 * g0.z) + (double)(s1 * g1.y) + (double)(s2 * g2.x) + (double)(s3 * g2.w);
    }
    __syncthreads();
    double* red = (double*)sd;        // data dead — reuse as f64 reduction buffer
    double v3[3] = {a0, a1, a2};
    #pragma unroll
    for (int kq = 0; kq < 3; kq++) {
        red[tid] = v3[kq];
        __syncthreads();
        for (int off = 256; off > 0; off >>= 1) {
            if (tid < off) red[tid] += red[tid + off];
            __syncthreads();
        }
        if (tid == 0) partials[((size_t)poly * 128 + c0_idx) * 3 + kq] = red[0];
        __syncthreads();
    }
}

// ---------- final commit reduce: 8 polys x 128 blocks x 3 comps -> 24 floats ----------
__global__ void reduce_commits_kernel(const double* __restrict__ partials, float* __restrict__ outf) {
    __shared__ double red[256];
    int t = threadIdx.x;
    for (int k = 0; k < 24; k++) {
        int p = k / 3, cc = k % 3;
        red[t] = (t < 128) ? partials[((size_t)p * 128 + t) * 3 + cc] : 0.0;
        __syncthreads();
        for (int off = 128; off > 0; off >>= 1) {
            if (t < off) red[t] += red[t + off];
            __syncthreads();
        }
        if (t == 0) outf[k] = (float)red[0];
        __syncthreads();
    }
}

extern "C" void kernel_launch(void* const* d_in, const int* in_sizes, int n_in,
                              void* d_out, int out_size, void* d_ws, size_t ws_size,
                              hipStream_t stream) {
    const int* wl = (const int*)d_in[0];
    const int* wr = (const int*)d_in[1];
    const int* wo = (const int*)d_in[2];
    const int* w4 = (const int*)d_in[3];
    const int* t1 = (const int*)d_in[4];
    const int* t2 = (const int*)d_in[5];
    const int* t3 = (const int*)d_in[6];
    const int* t4 = (const int*)d_in[7];
    const int* q  = (const int*)d_in[8];
    const float* g = (const float*)d_in[9];
    const int* zp = (const int*)d_in[10];

    char* ws = (char*)d_ws;
    // compact twiddle tables
    uint32_t* WT1  = (uint32_t*)(ws);                         // 16 KB
    uint32_t* ROWT = (uint32_t*)(ws + (64u  << 10));          // 2 KB
    uint32_t* CW   = (uint32_t*)(ws + (128u << 10));          // 144 KB
    uint32_t* tcomp  = (uint32_t*)(ws + (8ull  << 20));       // 8 MB
    uint32_t* fcomp  = (uint32_t*)(ws + (16ull << 20));       // 8 MB
    uint32_t* h1     = (uint32_t*)(ws + (24ull << 20));       // 8 MB
    uint32_t* h2     = (uint32_t*)(ws + (32ull << 20));       // 8 MB
    // small buffers at 64 KiB-aligned offsets
    unsigned int* hist    = (unsigned int*)(ws + (40ull << 20));                  // 32 KB
    unsigned int* basearr = (unsigned int*)(ws + (40ull << 20) + (64u  << 10));   // 32 KB+4
    unsigned int* fcursor = (unsigned int*)(ws + (40ull << 20) + (128u << 10));   // 32 KB
    unsigned int* hist64  = (unsigned int*)(ws + (40ull << 20) + (216u << 10));   // 256 B
    unsigned int* cbase   = (unsigned int*)(ws + (40ull << 20) + (224u << 10));   // 260 B
    unsigned int* ccursor = (unsigned int*)(ws + (40ull << 20) + (232u << 10));   // 256 B
    double*       partials = (double*)    (ws + (40ull << 20) + (256u << 10));    // 24 KB (8-aligned)

    float* outf = (float*)d_out;
    uint32_t* outpolys = (uint32_t*)outf + 24;                      // 8*N, final floats (16B-aligned)
    uint32_t* barr1 = (uint32_t*)outf + 1024;                       // 16 MB scratch (pre-NTT)
    uint32_t* barr2 = (uint32_t*)outf + 1024 + (5u << 20);          // 16 MB scratch (pre-NTT)

    hipMemsetAsync(hist, 0, NBUCK * sizeof(unsigned int), stream);
    hipMemsetAsync(hist64, 0, 64 * sizeof(unsigned int), stream);

    twiddle_all_kernel<<<144, 256, 0, stream>>>(WT1, ROWT, CW);

    compress_kernel<<<2048, 256, 0, stream>>>(wl, wr, wo, w4, t1, t2, t3, t4, q, zp,
                                              tcomp, fcomp, hist64);
    scan64_kernel<<<1, 64, 0, stream>>>(hist64, cbase, ccursor);
    pass1_kernel<<<1024, 256, 0, stream>>>(tcomp, fcomp, ccursor, barr1);
    fine_hist_kernel<<<dim3(16, 64), 256, 0, stream>>>(barr1, cbase, hist);
    scan_kernel<<<1, 256, 0, stream>>>(hist, basearr, fcursor);
    pass2_kernel<<<dim3(16, 64), 256, 0, stream>>>(barr1, cbase, fcursor, barr2);
    bucket_sort_kernel<<<NBUCK, 256, 0, stream>>>(barr2, basearr, h1, h2);

    SrcPtrs sp;
    sp.p[0] = (const uint32_t*)wl;
    sp.p[1] = (const uint32_t*)wr;
    sp.p[2] = (const uint32_t*)wo;
    sp.p[3] = (const uint32_t*)w4;
    sp.p[4] = tcomp;
    sp.p[5] = fcomp;
    sp.p[6] = h1;
    sp.p[7] = h2;
    ntt_phase1_kernel<<<4096, 256, 0, stream>>>(sp, outpolys, WT1);
    ntt_phase2_kernel<<<1024, 512, 0, stream>>>(outpolys, ROWT, CW, g, partials);

    reduce_commits_kernel<<<1, 256, 0, stream>>>(partials, outf);
}

// Round 15
// 325.398 us; speedup vs baseline: 1.0451x; 1.0451x over previous
//
#include <hip/hip_runtime.h>
#include <stdint.h>

#define PRIME 2013265921u
#define LOGN 21
#define NN (1u << LOGN)   // 2097152

// ---------- compile-time modular helpers ----------
constexpr uint32_t cpow(uint64_t b, uint64_t e) {
    uint64_t r = 1;
    b %= PRIME;
    while (e) {
        if (e & 1ull) r = r * b % PRIME;
        b = b * b % PRIME;
        e >>= 1;
    }
    return (uint32_t)r;
}
constexpr uint32_t cpinv() {           // PRIME^{-1} mod 2^32 (Newton)
    uint32_t inv = 1;
    for (int i = 0; i < 6; i++) inv *= 2u - PRIME * inv;
    return inv;
}
constexpr uint32_t NPRIME   = (uint32_t)(0u - cpinv());            // -P^{-1} mod 2^32
constexpr uint32_t RMODP    = (uint32_t)((1ull << 32) % PRIME);    // Mont(1)
constexpr uint32_t ROOT     = cpow(31u, (PRIME - 1) / NN);
constexpr uint32_t IROOT    = cpow(ROOT, PRIME - 2);
constexpr uint32_t NINV     = cpow(NN, PRIME - 2);
constexpr uint32_t NINV_M   = (uint32_t)((((uint64_t)NINV) << 32) % PRIME);  // Mont(N^-1)

// ---------- modular arithmetic ----------
__device__ __forceinline__ uint32_t addmod(uint32_t a, uint32_t b) {
    uint32_t s = a + b; return (s >= PRIME) ? s - PRIME : s;
}
__device__ __forceinline__ uint32_t submod(uint32_t a, uint32_t b) {
    return (a >= b) ? (a - b) : (a + PRIME - b);
}
__device__ __forceinline__ uint32_t mulmod(uint32_t a, uint32_t b) {
    return (uint32_t)(((uint64_t)a * (uint64_t)b) % PRIME);
}
// Montgomery: montmul(a_normal, Mont(b)) = a*b mod P; montmul(Mont(a),Mont(b)) = Mont(ab)
__device__ __forceinline__ uint32_t montmul(uint32_t a, uint32_t b) {
    uint64_t t = (uint64_t)a * b;
    uint32_t m = (uint32_t)t * NPRIME;
    uint32_t u = (uint32_t)((t + (uint64_t)m * PRIME) >> 32);
    return (u >= PRIME) ? u - PRIME : u;
}
__device__ uint32_t powmod(uint32_t b, uint32_t e) {
    uint32_t r = 1u;
    while (e) {
        if (e & 1u) r = mulmod(r, b);
        b = mulmod(b, b);
        e >>= 1;
    }
    return r;
}
__device__ __forceinline__ uint32_t tomont(uint32_t x) {
    return (uint32_t)((((uint64_t)x) << 32) % PRIME);
}

// ---------- twiddle tables (single dispatch, direct powmod) ----------
//   WT1[idx]  (idx<4096)  : WT1[2^s+j] = Mont(iroot^(j<<(20-s)))      (phase1 stage-packed)
//   ROWT[i]   (i<512)     : ROWT[2^t+kk] = Mont(iroot^(kk<<(20-t)))   (phase2 row factors)
//   CW[s*4096+j] (s<9)    : Mont(iroot^(j<<(8-s)))                     (phase2 col factors)
__global__ void twiddle_all_kernel(uint32_t* __restrict__ WT1, uint32_t* __restrict__ ROWT,
                                   uint32_t* __restrict__ CW) {
    uint32_t i = blockIdx.x * blockDim.x + threadIdx.x;   // < 36864
    if (i < 4096) {
        if (i == 0) WT1[0] = RMODP;
        else {
            uint32_t s = 31u - __clz(i);
            uint32_t j = i ^ (1u << s);
            WT1[i] = tomont(powmod(IROOT, j << (20u - s)));
        }
    }
    if (i < 512) {
        if (i == 0) ROWT[0] = RMODP;
        else {
            uint32_t t = 31u - __clz(i);
            ROWT[i] = tomont(powmod(IROOT, (i - (1u << t)) << (20u - t)));
        }
    }
    if (i < 36864) {
        uint32_t s = i >> 12, j = i & 4095u;
        CW[i] = tomont(powmod(IROOT, j << (8u - s)));
    }
}

// ---------- compress + fused coarse (64-bucket) histogram ----------
__global__ __launch_bounds__(256) void compress_kernel(
        const int* __restrict__ wl, const int* __restrict__ wr,
        const int* __restrict__ wo, const int* __restrict__ w4,
        const int* __restrict__ t1, const int* __restrict__ t2,
        const int* __restrict__ t3, const int* __restrict__ t4,
        const int* __restrict__ q,  const int* __restrict__ zp,
        uint32_t* __restrict__ tcomp, uint32_t* __restrict__ fcomp,
        unsigned int* __restrict__ hist64) {
    __shared__ unsigned int h64[64];
    if (threadIdx.x < 64) h64[threadIdx.x] = 0;
    __syncthreads();
    uint32_t z1 = ((uint32_t)zp[0]) % PRIME;
    uint32_t z2 = mulmod(z1, z1);
    uint32_t z3 = mulmod(z2, z1);
    for (uint32_t i = blockIdx.x * blockDim.x + threadIdx.x; i < NN; i += gridDim.x * blockDim.x) {
        uint32_t t = addmod(addmod((uint32_t)t1[i], mulmod((uint32_t)t2[i], z1)),
                            addmod(mulmod((uint32_t)t3[i], z2), mulmod((uint32_t)t4[i], z3)));
        uint32_t w = addmod(addmod((uint32_t)wl[i], mulmod((uint32_t)wr[i], z1)),
                            addmod(mulmod((uint32_t)wo[i], z2), mulmod((uint32_t)w4[i], z3)));
        uint32_t f = (q[i] != 0) ? w : t;
        tcomp[i] = t;
        fcomp[i] = f;
        atomicAdd(&h64[t >> 25], 1u);
        atomicAdd(&h64[f >> 25], 1u);
    }
    __syncthreads();
    if (threadIdx.x < 64 && h64[threadIdx.x])
        atomicAdd(&hist64[threadIdx.x], h64[threadIdx.x]);
}

// ---------- sort ----------
#define NBUCK 8192

__global__ void scan64_kernel(const unsigned int* __restrict__ hist64,
                              unsigned int* __restrict__ cbase, unsigned int* __restrict__ ccursor) {
    if (threadIdx.x == 0) {
        unsigned int run = 0;
        for (int b = 0; b < 64; b++) { cbase[b] = run; ccursor[b] = run; run += hist64[b]; }
        cbase[64] = run;
    }
}

// pass 1: scatter into 64 coarse buckets with LDS grouping (coalesced run writes)
__global__ __launch_bounds__(256) void pass1_kernel(const uint32_t* __restrict__ tcomp,
                                                    const uint32_t* __restrict__ fcomp,
                                                    unsigned int* __restrict__ ccursor,
                                                    uint32_t* __restrict__ barr1) {
    __shared__ uint32_t grp[4096];
    __shared__ unsigned char grpb[4096];
    __shared__ unsigned int cnt[64], pref[64], curs[64], rbase[64];
    uint32_t base = blockIdx.x * 4096;    // grid 1024 covers 2NN exactly
    uint32_t tid = threadIdx.x;
    if (tid < 64) cnt[tid] = 0;
    __syncthreads();
    for (uint32_t l = tid; l < 4096; l += 256) {
        uint32_t gi = base + l;
        uint32_t v = (gi < NN) ? tcomp[gi] : fcomp[gi - NN];
        atomicAdd(&cnt[v >> 25], 1u);
    }
    __syncthreads();
    if (tid == 0) {
        unsigned int run = 0;
        for (int b = 0; b < 64; b++) { pref[b] = run; curs[b] = run; run += cnt[b]; }
    }
    __syncthreads();
    if (tid < 64 && cnt[tid]) rbase[tid] = atomicAdd(&ccursor[tid], cnt[tid]);
    for (uint32_t l = tid; l < 4096; l += 256) {
        uint32_t gi = base + l;
        uint32_t v = (gi < NN) ? tcomp[gi] : fcomp[gi - NN];
        uint32_t b = v >> 25;
        unsigned int p = atomicAdd(&curs[b], 1u);
        grp[p] = v; grpb[p] = (unsigned char)b;
    }
    __syncthreads();
    for (uint32_t l = tid; l < 4096; l += 256) {
        uint32_t b = grpb[l];
        barr1[rbase[b] + (l - pref[b])] = grp[l];
    }
}

// fine (8192-bucket) histogram from coarse-partitioned data
__global__ __launch_bounds__(256) void fine_hist_kernel(const uint32_t* __restrict__ barr1,
                                                        const unsigned int* __restrict__ cbase,
                                                        unsigned int* __restrict__ hist) {
    __shared__ unsigned int cnt[128];
    uint32_t tid = threadIdx.x;
    uint32_t reg = blockIdx.y;
    if (tid < 128) cnt[tid] = 0;
    __syncthreads();
    uint32_t lo = cbase[reg], hi = cbase[reg + 1];
    for (uint32_t i = lo + blockIdx.x * 256 + tid; i < hi; i += gridDim.x * 256)
        atomicAdd(&cnt[(barr1[i] >> 18) & 127u], 1u);
    __syncthreads();
    if (tid < 128 && cnt[tid]) atomicAdd(&hist[reg * 128 + tid], cnt[tid]);
}

__global__ void scan_kernel(const unsigned int* __restrict__ hist,
                            unsigned int* __restrict__ basearr, unsigned int* __restrict__ fcursor) {
    __shared__ unsigned int ls[256];
    int t = threadIdx.x;
    unsigned int local[32];
    unsigned int s = 0;
    for (int k = 0; k < 32; k++) { local[k] = hist[t * 32 + k]; s += local[k]; }
    ls[t] = s;
    __syncthreads();
    for (int off = 1; off < 256; off <<= 1) {
        unsigned int v = (t >= off) ? ls[t - off] : 0u;
        __syncthreads();
        ls[t] += v;
        __syncthreads();
    }
    unsigned int run = ls[t] - s;  // exclusive prefix
    for (int k = 0; k < 32; k++) {
        basearr[t * 32 + k] = run;
        fcursor[t * 32 + k] = run;
        run += local[k];
    }
    if (t == 255) basearr[NBUCK] = run;
}

// pass 2: within each coarse region, scatter into 128 fine buckets (LDS grouping)
__global__ __launch_bounds__(256) void pass2_kernel(const uint32_t* __restrict__ barr1,
                                                    const unsigned int* __restrict__ cbase,
                                                    unsigned int* __restrict__ fcursor,
                                                    uint32_t* __restrict__ barr2) {
    __shared__ uint32_t grp[4096];
    __shared__ unsigned char grpb[4096];
    __shared__ unsigned int cnt[128], pref[128], curs[128], rbase[128];
    uint32_t tid = threadIdx.x;
    uint32_t reg = blockIdx.y;
    uint32_t lo = cbase[reg], hi = cbase[reg + 1];
    for (uint32_t start = lo + blockIdx.x * 4096; start < hi; start += gridDim.x * 4096) {
        uint32_t n = min(4096u, hi - start);
        if (tid < 128) cnt[tid] = 0;
        __syncthreads();
        for (uint32_t l = tid; l < n; l += 256)
            atomicAdd(&cnt[(barr1[start + l] >> 18) & 127u], 1u);
        __syncthreads();
        if (tid == 0) {
            unsigned int run = 0;
            for (int b = 0; b < 128; b++) { pref[b] = run; curs[b] = run; run += cnt[b]; }
        }
        __syncthreads();
        if (tid < 128 && cnt[tid]) rbase[tid] = atomicAdd(&fcursor[reg * 128 + tid], cnt[tid]);
        for (uint32_t l = tid; l < n; l += 256) {
            uint32_t v = barr1[start + l];
            uint32_t b = (v >> 18) & 127u;
            unsigned int p = atomicAdd(&curs[b], 1u);
            grp[p] = v; grpb[p] = (unsigned char)b;
        }
        __syncthreads();
        for (uint32_t l = tid; l < n; l += 256) {
            uint32_t b = grpb[l];
            barr2[rbase[b] + (l - pref[b])] = grp[l];
        }
        __syncthreads();
    }
}

// ---------- per-bucket O(n) MSD counting sort (128 sub-bins, bits 17:11) ----------
__global__ __launch_bounds__(256) void bucket_sort_kernel(const uint32_t* __restrict__ barr,
                                                          const unsigned int* __restrict__ basearr,
                                                          uint32_t* __restrict__ h1, uint32_t* __restrict__ h2) {
    __shared__ uint32_t ord[4096];
    __shared__ unsigned int cnt[128], pref[128], curs[128];
    uint32_t b  = blockIdx.x;
    uint32_t lo = basearr[b], hi = basearr[b + 1];
    uint32_t n  = hi - lo;
    if (n == 0) return;
    if (n > 4096) n = 4096;   // unreachable for this distribution
    uint32_t tid = threadIdx.x;
    if (tid < 128) cnt[tid] = 0;
    __syncthreads();
    for (uint32_t i = tid; i < n; i += 256)
        atomicAdd(&cnt[(barr[lo + i] >> 11) & 127u], 1u);
    __syncthreads();
    if (tid == 0) {
        unsigned int run = 0;
        for (int d = 0; d < 128; d++) { pref[d] = run; curs[d] = run; run += cnt[d]; }
    }
    __syncthreads();
    for (uint32_t i = tid; i < n; i += 256) {
        uint32_t v = barr[lo + i];
        uint32_t d = (v >> 11) & 127u;
        unsigned int p = atomicAdd(&curs[d], 1u);
        ord[p] = v;
    }
    __syncthreads();
    for (uint32_t p = tid; p < n; p += 256) {
        uint32_t v = ord[p];
        uint32_t d = (v >> 11) & 127u;
        uint32_t l0 = pref[d], l1 = l0 + cnt[d];
        uint32_t r = 0;
        for (uint32_t qq = l0; qq < l1; qq++) {
            uint32_t u = ord[qq];
            r += (u < v) || (u == v && qq < p);
        }
        uint32_t gp = lo + l0 + r;
        if (gp & 1) h2[gp >> 1] = v; else h1[gp >> 1] = v;
    }
}

// ---------- bit-reversal permute: dst[i] = src[rev21(i)], tiled ----------
struct SrcPtrs { const uint32_t* p[8]; };

__global__ void bitrev_kernel(SrcPtrs srcs, uint32_t* __restrict__ dst) {
    __shared__ uint32_t tile[64 * 65];
    uint32_t poly = blockIdx.y;
    const uint32_t* src = srcs.p[poly];
    uint32_t* out = dst + (size_t)poly * NN;
    uint32_t m  = blockIdx.x;                 // 9-bit middle
    uint32_t rm = __brev(m) >> 23;            // rev9
    for (uint32_t l = threadIdx.x; l < 4096; l += blockDim.x) {
        uint32_t u = l >> 6, v = l & 63;
        tile[u * 65 + v] = src[(u << 15) | (rm << 6) | v];
    }
    __syncthreads();
    for (uint32_t l = threadIdx.x; l < 4096; l += blockDim.x) {
        uint32_t a = l >> 6, b = l & 63;
        uint32_t ra = __brev(a) >> 26, rb = __brev(b) >> 26;  // rev6
        out[(a << 15) | (m << 6) | b] = tile[rb * 65 + ra];
    }
}

// ---------- NTT stages 1..12, radix-4 (6 rounds); uint4 global I/O; twiddles in LDS ----------
// w2j trick: W_{s+1}[j]*J = W_{s+1}[j+h]  -> wt[3h+j], no montmul.
__device__ __forceinline__ uint32_t padi(uint32_t i) { return i + (i >> 5); }

__global__ __launch_bounds__(256) void ntt_phase1_kernel(uint32_t* __restrict__ polys,
                                                         const uint32_t* __restrict__ WT1) {
    __shared__ uint32_t wt[4096];
    __shared__ uint32_t sd[4224];     // padded: i + (i>>5)
    uint32_t* x = polys + (size_t)blockIdx.y * NN + (size_t)blockIdx.x * 4096;
    // vectorized load: 4 x uint4 per thread (global), scalar LDS scatter (padi)
    #pragma unroll
    for (uint32_t m = 0; m < 4; m++) {
        uint32_t l = m * 1024 + threadIdx.x * 4;
        uint4 v = *reinterpret_cast<const uint4*>(&x[l]);
        uint4 w = *reinterpret_cast<const uint4*>(&WT1[l]);
        uint32_t p = padi(l);           // l%32 in {0,4,..,28}: 4-group stays contiguous
        sd[p] = v.x; sd[p + 1] = v.y; sd[p + 2] = v.z; sd[p + 3] = v.w;
        *reinterpret_cast<uint4*>(&wt[l]) = w;
    }
    __syncthreads();
    // 6 radix-4 rounds = stage pairs (1,2),(3,4),...,(11,12)
    #pragma unroll
    for (int t = 0; t < 6; t++) {
        uint32_t h = 1u << (2 * t);
        #pragma unroll
        for (uint32_t m = 0; m < 4; m++) {
            uint32_t q = threadIdx.x + (m << 8);     // unit 0..1023
            uint32_t j = q & (h - 1);
            uint32_t grp = q >> (2 * t);
            uint32_t i0 = (grp << (2 * t + 2)) + j;
            uint32_t w1  = wt[h + j];
            uint32_t w2  = wt[2 * h + j];
            uint32_t w2j = wt[3 * h + j];
            uint32_t p0 = padi(i0), p1 = padi(i0 + h), p2 = padi(i0 + 2 * h), p3 = padi(i0 + 3 * h);
            uint32_t a0 = sd[p0], a1 = sd[p1], a2 = sd[p2], a3 = sd[p3];
            uint32_t t1 = montmul(w1, a1), t3 = montmul(w1, a3);
            uint32_t b0 = addmod(a0, t1), b1 = submod(a0, t1);
            uint32_t b2 = addmod(a2, t3), b3 = submod(a2, t3);
            uint32_t u2 = montmul(w2, b2), u3 = montmul(w2j, b3);
            sd[p0] = addmod(b0, u2);
            sd[p2] = submod(b0, u2);
            sd[p1] = addmod(b1, u3);
            sd[p3] = submod(b1, u3);
        }
        __syncthreads();
    }
    // fold in N^-1 scaling; vectorized store
    #pragma unroll
    for (uint32_t m = 0; m < 4; m++) {
        uint32_t l = m * 1024 + threadIdx.x * 4;
        uint32_t p = padi(l);
        uint4 v;
        v.x = montmul(sd[p], NINV_M);
        v.y = montmul(sd[p + 1], NINV_M);
        v.z = montmul(sd[p + 2], NINV_M);
        v.w = montmul(sd[p + 3], NINV_M);
        *reinterpret_cast<uint4*>(&x[l]) = v;
    }
}

// ---------- NTT stages 13..21: 32-col x 512-row tile (64KB LDS, conflict-free);
//            uint4/float4 global I/O; radix-4 x4 + radix-2; fused commit; XCD remap ----------
__global__ __launch_bounds__(512) void ntt_phase2_kernel(uint32_t* __restrict__ polys,
                                                         const uint32_t* __restrict__ ROWT,
                                                         const uint32_t* __restrict__ CW,
                                                         const float* __restrict__ g,
                                                         double* __restrict__ partials) {
    __shared__ __align__(16) uint32_t sd[16384];    // [row:512][col:32] — 64 KB, banks ≡ col
    // XCD-aware, poly-major remap (concurrent blocks: adjacent 32-col slices of same poly)
    uint32_t b = blockIdx.x;              // 0..1023
    uint32_t xcd = b & 7u, k = b >> 3;    // k: 0..127
    uint32_t poly = k >> 4;               // 0..7
    uint32_t c0_idx = xcd * 16u + (k & 15u);   // 0..127
    uint32_t* x = polys + (size_t)poly * NN;
    uint32_t c0 = c0_idx * 32u;
    uint32_t tid = threadIdx.x;           // 0..511
    uint32_t c = tid & 31u;
    uint32_t rt = tid >> 5;               // 0..15
    uint32_t cg = tid & 7u;               // col group (4 cols)
    uint32_t r0 = tid >> 3;               // 0..63

    // vectorized load: 8 x uint4 per thread; LDS uint4 store (aligned, banks 4cg..4cg+3)
    #pragma unroll
    for (uint32_t kk = 0; kk < 8; kk++) {
        uint32_t row = r0 + kk * 64;
        uint4 v = *reinterpret_cast<const uint4*>(&x[(row << 12) + c0 + 4 * cg]);
        *reinterpret_cast<uint4*>(&sd[row * 32 + 4 * cg]) = v;
    }
    uint32_t cw[9];
    #pragma unroll
    for (int s = 0; s < 9; s++) cw[s] = CW[s * 4096 + c0 + c];
    __syncthreads();

    // 4 radix-4 rounds (local stage pairs); w2j = ROWT[3h+kk]*cw[s+1]
    #pragma unroll
    for (int s = 0; s < 8; s += 2) {
        uint32_t h = 1u << s;
        #pragma unroll
        for (uint32_t m = 0; m < 8; m++) {
            uint32_t u = (rt << 3) + m;          // radix-4 unit 0..127
            uint32_t kk = u & (h - 1);
            uint32_t grp = u >> s;
            uint32_t r = (grp << (s + 2)) + kk;
            uint32_t w1  = montmul(ROWT[h + kk], cw[s]);
            uint32_t w2  = montmul(ROWT[2 * h + kk], cw[s + 1]);
            uint32_t w2j = montmul(ROWT[3 * h + kk], cw[s + 1]);
            uint32_t i0 = (r << 5) + c;
            uint32_t i1 = ((r + h) << 5) + c;
            uint32_t i2 = ((r + 2 * h) << 5) + c;
            uint32_t i3 = ((r + 3 * h) << 5) + c;
            uint32_t a0 = sd[i0], a1 = sd[i1], a2 = sd[i2], a3 = sd[i3];
            uint32_t t1 = montmul(w1, a1), t3 = montmul(w1, a3);
            uint32_t b0 = addmod(a0, t1), b1 = submod(a0, t1);
            uint32_t b2 = addmod(a2, t3), b3 = submod(a2, t3);
            uint32_t u2 = montmul(w2, b2), u3 = montmul(w2j, b3);
            sd[i0] = addmod(b0, u2);
            sd[i2] = submod(b0, u2);
            sd[i1] = addmod(b1, u3);
            sd[i3] = submod(b1, u3);
        }
        __syncthreads();
    }
    // final radix-2 stage (local s=8, h=256)
    #pragma unroll
    for (uint32_t m = 0; m < 16; m++) {
        uint32_t kk = (rt << 4) + m;       // 0..255
        uint32_t w = montmul(ROWT[256 + kk], cw[8]);
        uint32_t i0 = (kk << 5) + c, i1 = ((kk + 256) << 5) + c;
        uint32_t u = sd[i0];
        uint32_t v = montmul(sd[i1], w);
        sd[i0] = addmod(u, v);
        sd[i1] = submod(u, v);
    }
    __syncthreads();

    // epilogue: float4 poly store + 3x float4 g loads per 4 elems + fused commit
    float* xf = (float*)x;
    const float invp = (float)(1.0 / 2013265921.0);
    double a0 = 0.0, a1 = 0.0, a2 = 0.0;
    #pragma unroll
    for (uint32_t kk = 0; kk < 8; kk++) {
        uint32_t row = r0 + kk * 64;
        uint32_t idx0 = (row << 12) + c0 + 4 * cg;
        uint32_t base = row * 32 + 4 * cg;
        float f0 = (float)sd[base], f1 = (float)sd[base + 1];
        float f2 = (float)sd[base + 2], f3 = (float)sd[base + 3];
        float4 fv = make_float4(f0, f1, f2, f3);
        *reinterpret_cast<float4*>(&xf[idx0]) = fv;
        // g rows for 4 elems: 48 B, 16B-aligned (idx0 % 4 == 0)
        const float4* gp = reinterpret_cast<const float4*>(&g[(size_t)idx0 * 3]);
        float4 g0 = gp[0], g1 = gp[1], g2 = gp[2];
        float s0 = f0 * invp, s1 = f1 * invp, s2 = f2 * invp, s3 = f3 * invp;
        a0 += (double)(s0 * g0.x) + (double)(s1 * g0.w) + (double)(s2 * g1.z) + (double)(s3 * g2.y);
        a1 += (double)(s0 * g0.y) + (double)(s1 * g1.x) + (double)(s2 * g1.w) + (double)(s3 * g2.z);
        a2 += (double)(s0 * g0.z) + (double)(s1 * g1.y) + (double)(s2 * g2.x) + (double)(s3 * g2.w);
    }
    __syncthreads();
    // data in sd is dead — reuse as f64 reduction buffer
    double* red = (double*)sd;        // 512 doubles = 4 KB
    double v3[3] = {a0, a1, a2};
    #pragma unroll
    for (int kq = 0; kq < 3; kq++) {
        red[tid] = v3[kq];
        __syncthreads();
        for (int off = 256; off > 0; off >>= 1) {
            if (tid < off) red[tid] += red[tid + off];
            __syncthreads();
        }
        if (tid == 0) partials[((size_t)poly * 128 + c0_idx) * 3 + kq] = red[0];
        __syncthreads();
    }
}

// ---------- final commit reduce: 8 polys x 128 blocks x 3 comps -> 24 floats ----------
__global__ void reduce_commits_kernel(const double* __restrict__ partials, float* __restrict__ outf) {
    __shared__ double red[256];
    int t = threadIdx.x;
    for (int k = 0; k < 24; k++) {
        int p = k / 3, cc = k % 3;
        red[t] = (t < 128) ? partials[((size_t)p * 128 + t) * 3 + cc] : 0.0;
        __syncthreads();
        for (int off = 128; off > 0; off >>= 1) {
            if (t < off) red[t] += red[t + off];
            __syncthreads();
        }
        if (t == 0) outf[k] = (float)red[0];
        __syncthreads();
    }
}

extern "C" void kernel_launch(void* const* d_in, const int* in_sizes, int n_in,
                              void* d_out, int out_size, void* d_ws, size_t ws_size,
                              hipStream_t stream) {
    const int* wl = (const int*)d_in[0];
    const int* wr = (const int*)d_in[1];
    const int* wo = (const int*)d_in[2];
    const int* w4 = (const int*)d_in[3];
    const int* t1 = (const int*)d_in[4];
    const int* t2 = (const int*)d_in[5];
    const int* t3 = (const int*)d_in[6];
    const int* t4 = (const int*)d_in[7];
    const int* q  = (const int*)d_in[8];
    const float* g = (const float*)d_in[9];
    const int* zp = (const int*)d_in[10];

    char* ws = (char*)d_ws;
    // compact twiddle tables
    uint32_t* WT1  = (uint32_t*)(ws);                         // 16 KB
    uint32_t* ROWT = (uint32_t*)(ws + (64u  << 10));          // 2 KB
    uint32_t* CW   = (uint32_t*)(ws + (128u << 10));          // 144 KB
    uint32_t* tcomp  = (uint32_t*)(ws + (8ull  << 20));       // 8 MB
    uint32_t* fcomp  = (uint32_t*)(ws + (16ull << 20));       // 8 MB
    uint32_t* h1     = (uint32_t*)(ws + (24ull << 20));       // 8 MB
    uint32_t* h2     = (uint32_t*)(ws + (32ull << 20));       // 8 MB
    // small buffers at 64 KiB-aligned offsets
    unsigned int* hist    = (unsigned int*)(ws + (40ull << 20));                  // 32 KB
    unsigned int* basearr = (unsigned int*)(ws + (40ull << 20) + (64u  << 10));   // 32 KB+4
    unsigned int* fcursor = (unsigned int*)(ws + (40ull << 20) + (128u << 10));   // 32 KB
    unsigned int* hist64  = (unsigned int*)(ws + (40ull << 20) + (216u << 10));   // 256 B
    unsigned int* cbase   = (unsigned int*)(ws + (40ull << 20) + (224u << 10));   // 260 B
    unsigned int* ccursor = (unsigned int*)(ws + (40ull << 20) + (232u << 10));   // 256 B
    double*       partials = (double*)    (ws + (40ull << 20) + (256u << 10));    // 24 KB (8-aligned)

    float* outf = (float*)d_out;
    uint32_t* outpolys = (uint32_t*)outf + 24;                      // 8*N, final floats (16B-aligned)
    uint32_t* barr1 = (uint32_t*)outf + 1024;                       // 16 MB scratch (pre-NTT)
    uint32_t* barr2 = (uint32_t*)outf + 1024 + (5u << 20);          // 16 MB scratch (pre-NTT)

    hipMemsetAsync(hist, 0, NBUCK * sizeof(unsigned int), stream);
    hipMemsetAsync(hist64, 0, 64 * sizeof(unsigned int), stream);

    twiddle_all_kernel<<<144, 256, 0, stream>>>(WT1, ROWT, CW);

    compress_kernel<<<2048, 256, 0, stream>>>(wl, wr, wo, w4, t1, t2, t3, t4, q, zp,
                                              tcomp, fcomp, hist64);
    scan64_kernel<<<1, 64, 0, stream>>>(hist64, cbase, ccursor);
    pass1_kernel<<<1024, 256, 0, stream>>>(tcomp, fcomp, ccursor, barr1);
    fine_hist_kernel<<<dim3(16, 64), 256, 0, stream>>>(barr1, cbase, hist);
    scan_kernel<<<1, 256, 0, stream>>>(hist, basearr, fcursor);
    pass2_kernel<<<dim3(16, 64), 256, 0, stream>>>(barr1, cbase, fcursor, barr2);
    bucket_sort_kernel<<<NBUCK, 256, 0, stream>>>(barr2, basearr, h1, h2);

    SrcPtrs sp;
    sp.p[0] = (const uint32_t*)wl;
    sp.p[1] = (const uint32_t*)wr;
    sp.p[2] = (const uint32_t*)wo;
    sp.p[3] = (const uint32_t*)w4;
    sp.p[4] = tcomp;
    sp.p[5] = fcomp;
    sp.p[6] = h1;
    sp.p[7] = h2;
    bitrev_kernel<<<dim3(512, 8), 256, 0, stream>>>(sp, outpolys);
    ntt_phase1_kernel<<<dim3(512, 8), 256, 0, stream>>>(outpolys, WT1);
    ntt_phase2_kernel<<<1024, 512, 0, stream>>>(outpolys, ROWT, CW, g, partials);

    reduce_commits_kernel<<<1, 256, 0, stream>>>(partials, outf);
}

// Round 16
// 276.821 us; speedup vs baseline: 1.2285x; 1.1755x over previous
//
#include <hip/hip_runtime.h>
#include <stdint.h>

#define PRIME 2013265921u
#define LOGN 21
#define NN (1u << LOGN)   // 2097152
#define REG 73728u        // padded coarse-region size: 2NN/60 (~69906) + 14.6 sigma

// ---------- compile-time modular helpers ----------
constexpr uint32_t cpow(uint64_t b, uint64_t e) {
    uint64_t r = 1;
    b %= PRIME;
    while (e) {
        if (e & 1ull) r = r * b % PRIME;
        b = b * b % PRIME;
        e >>= 1;
    }
    return (uint32_t)r;
}
constexpr uint32_t cpinv() {           // PRIME^{-1} mod 2^32 (Newton)
    uint32_t inv = 1;
    for (int i = 0; i < 6; i++) inv *= 2u - PRIME * inv;
    return inv;
}
constexpr uint32_t NPRIME   = (uint32_t)(0u - cpinv());            // -P^{-1} mod 2^32
constexpr uint32_t RMODP    = (uint32_t)((1ull << 32) % PRIME);    // Mont(1)
constexpr uint32_t ROOT     = cpow(31u, (PRIME - 1) / NN);
constexpr uint32_t IROOT    = cpow(ROOT, PRIME - 2);
constexpr uint32_t NINV     = cpow(NN, PRIME - 2);
constexpr uint32_t NINV_M   = (uint32_t)((((uint64_t)NINV) << 32) % PRIME);  // Mont(N^-1)

// ---------- modular arithmetic ----------
__device__ __forceinline__ uint32_t addmod(uint32_t a, uint32_t b) {
    uint32_t s = a + b; return (s >= PRIME) ? s - PRIME : s;
}
__device__ __forceinline__ uint32_t submod(uint32_t a, uint32_t b) {
    return (a >= b) ? (a - b) : (a + PRIME - b);
}
__device__ __forceinline__ uint32_t mulmod(uint32_t a, uint32_t b) {
    return (uint32_t)(((uint64_t)a * (uint64_t)b) % PRIME);
}
// Montgomery: montmul(a_normal, Mont(b)) = a*b mod P; montmul(Mont(a),Mont(b)) = Mont(ab)
__device__ __forceinline__ uint32_t montmul(uint32_t a, uint32_t b) {
    uint64_t t = (uint64_t)a * b;
    uint32_t m = (uint32_t)t * NPRIME;
    uint32_t u = (uint32_t)((t + (uint64_t)m * PRIME) >> 32);
    return (u >= PRIME) ? u - PRIME : u;
}
__device__ uint32_t powmod(uint32_t b, uint32_t e) {
    uint32_t r = 1u;
    while (e) {
        if (e & 1u) r = mulmod(r, b);
        b = mulmod(b, b);
        e >>= 1;
    }
    return r;
}
__device__ __forceinline__ uint32_t tomont(uint32_t x) {
    return (uint32_t)((((uint64_t)x) << 32) % PRIME);
}

// ---------- twiddle tables (single dispatch, direct powmod) ----------
__global__ void twiddle_all_kernel(uint32_t* __restrict__ WT1, uint32_t* __restrict__ ROWT,
                                   uint32_t* __restrict__ CW) {
    uint32_t i = blockIdx.x * blockDim.x + threadIdx.x;   // < 36864
    if (i < 4096) {
        if (i == 0) WT1[0] = RMODP;
        else {
            uint32_t s = 31u - __clz(i);
            uint32_t j = i ^ (1u << s);
            WT1[i] = tomont(powmod(IROOT, j << (20u - s)));
        }
    }
    if (i < 512) {
        if (i == 0) ROWT[0] = RMODP;
        else {
            uint32_t t = 31u - __clz(i);
            ROWT[i] = tomont(powmod(IROOT, (i - (1u << t)) << (20u - t)));
        }
    }
    if (i < 36864) {
        uint32_t s = i >> 12, j = i & 4095u;
        CW[i] = tomont(powmod(IROOT, j << (8u - s)));
    }
}

// ---------- cursor init: region b starts at b*REG ----------
__global__ void init_cursor_kernel(unsigned int* __restrict__ ccursor) {
    if (threadIdx.x < 64) ccursor[threadIdx.x] = threadIdx.x * REG;
}

// ---------- FUSED compress + coarse scatter (static padded regions, LDS grouping) ----------
__global__ __launch_bounds__(256) void compress_scatter_kernel(
        const int* __restrict__ wl, const int* __restrict__ wr,
        const int* __restrict__ wo, const int* __restrict__ w4,
        const int* __restrict__ t1, const int* __restrict__ t2,
        const int* __restrict__ t3, const int* __restrict__ t4,
        const int* __restrict__ q,  const int* __restrict__ zp,
        uint32_t* __restrict__ tcomp, uint32_t* __restrict__ fcomp,
        unsigned int* __restrict__ ccursor, uint32_t* __restrict__ barr1) {
    __shared__ uint32_t grp[4096];
    __shared__ unsigned char grpb[4096];
    __shared__ unsigned int cnt[64], pref[64], curs[64], rbase[64];
    uint32_t tid = threadIdx.x;
    uint32_t i0 = blockIdx.x * 2048u + tid * 8u;    // grid 1024 covers NN exactly
    if (tid < 64) cnt[tid] = 0;
    __syncthreads();

    uint32_t z1 = ((uint32_t)zp[0]) % PRIME;
    uint32_t z2 = mulmod(z1, z1);
    uint32_t z3 = mulmod(z2, z1);
    uint32_t tv[8], fv[8];
    #pragma unroll
    for (int h = 0; h < 2; h++) {
        uint32_t ib = i0 + (uint32_t)h * 4u;
        int4 a1 = *reinterpret_cast<const int4*>(&t1[ib]);
        int4 a2 = *reinterpret_cast<const int4*>(&t2[ib]);
        int4 a3 = *reinterpret_cast<const int4*>(&t3[ib]);
        int4 a4 = *reinterpret_cast<const int4*>(&t4[ib]);
        int4 b1 = *reinterpret_cast<const int4*>(&wl[ib]);
        int4 b2 = *reinterpret_cast<const int4*>(&wr[ib]);
        int4 b3 = *reinterpret_cast<const int4*>(&wo[ib]);
        int4 b4 = *reinterpret_cast<const int4*>(&w4[ib]);
        int4 qq = *reinterpret_cast<const int4*>(&q[ib]);
        int av1[4] = {a1.x, a1.y, a1.z, a1.w};
        int av2[4] = {a2.x, a2.y, a2.z, a2.w};
        int av3[4] = {a3.x, a3.y, a3.z, a3.w};
        int av4[4] = {a4.x, a4.y, a4.z, a4.w};
        int bv1[4] = {b1.x, b1.y, b1.z, b1.w};
        int bv2[4] = {b2.x, b2.y, b2.z, b2.w};
        int bv3[4] = {b3.x, b3.y, b3.z, b3.w};
        int bv4[4] = {b4.x, b4.y, b4.z, b4.w};
        int qv[4]  = {qq.x, qq.y, qq.z, qq.w};
        #pragma unroll
        for (int j = 0; j < 4; j++) {
            uint32_t t = addmod(addmod((uint32_t)av1[j], mulmod((uint32_t)av2[j], z1)),
                                addmod(mulmod((uint32_t)av3[j], z2), mulmod((uint32_t)av4[j], z3)));
            uint32_t w = addmod(addmod((uint32_t)bv1[j], mulmod((uint32_t)bv2[j], z1)),
                                addmod(mulmod((uint32_t)bv3[j], z2), mulmod((uint32_t)bv4[j], z3)));
            tv[h * 4 + j] = t;
            fv[h * 4 + j] = (qv[j] != 0) ? w : t;
        }
    }
    // store compressed streams (needed later as NTT inputs)
    *reinterpret_cast<uint4*>(&tcomp[i0])     = make_uint4(tv[0], tv[1], tv[2], tv[3]);
    *reinterpret_cast<uint4*>(&tcomp[i0 + 4]) = make_uint4(tv[4], tv[5], tv[6], tv[7]);
    *reinterpret_cast<uint4*>(&fcomp[i0])     = make_uint4(fv[0], fv[1], fv[2], fv[3]);
    *reinterpret_cast<uint4*>(&fcomp[i0 + 4]) = make_uint4(fv[4], fv[5], fv[6], fv[7]);

    // block-local coarse histogram over the 4096 values (2048 t + 2048 f)
    #pragma unroll
    for (int j = 0; j < 8; j++) {
        atomicAdd(&cnt[tv[j] >> 25], 1u);
        atomicAdd(&cnt[fv[j] >> 25], 1u);
    }
    __syncthreads();
    if (tid == 0) {
        unsigned int run = 0;
        for (int b = 0; b < 64; b++) { pref[b] = run; curs[b] = run; run += cnt[b]; }
    }
    __syncthreads();
    if (tid < 64 && cnt[tid]) rbase[tid] = atomicAdd(&ccursor[tid], cnt[tid]);
    // group into LDS by coarse bucket
    #pragma unroll
    for (int j = 0; j < 8; j++) {
        uint32_t v = tv[j];
        uint32_t b = v >> 25;
        unsigned int p = atomicAdd(&curs[b], 1u);
        grp[p] = v; grpb[p] = (unsigned char)b;
    }
    #pragma unroll
    for (int j = 0; j < 8; j++) {
        uint32_t v = fv[j];
        uint32_t b = v >> 25;
        unsigned int p = atomicAdd(&curs[b], 1u);
        grp[p] = v; grpb[p] = (unsigned char)b;
    }
    __syncthreads();
    // coalesced run writes into padded coarse regions
    for (uint32_t l = tid; l < 4096; l += 256) {
        uint32_t b = grpb[l];
        barr1[rbase[b] + (l - pref[b])] = grp[l];
    }
}

// ---------- sort ----------
#define NBUCK 8192

// fine (8192-bucket) histogram from coarse-partitioned (padded) data
__global__ __launch_bounds__(256) void fine_hist_kernel(const uint32_t* __restrict__ barr1,
                                                        const unsigned int* __restrict__ ccursor,
                                                        unsigned int* __restrict__ hist) {
    __shared__ unsigned int cnt[128];
    uint32_t tid = threadIdx.x;
    uint32_t reg = blockIdx.y;
    if (tid < 128) cnt[tid] = 0;
    __syncthreads();
    uint32_t lo = reg * REG, hi = ccursor[reg];
    for (uint32_t i = lo + blockIdx.x * 256 + tid; i < hi; i += gridDim.x * 256)
        atomicAdd(&cnt[(barr1[i] >> 18) & 127u], 1u);
    __syncthreads();
    if (tid < 128 && cnt[tid]) atomicAdd(&hist[reg * 128 + tid], cnt[tid]);
}

__global__ void scan_kernel(const unsigned int* __restrict__ hist,
                            unsigned int* __restrict__ basearr, unsigned int* __restrict__ fcursor) {
    __shared__ unsigned int ls[256];
    int t = threadIdx.x;
    unsigned int local[32];
    unsigned int s = 0;
    for (int k = 0; k < 32; k++) { local[k] = hist[t * 32 + k]; s += local[k]; }
    ls[t] = s;
    __syncthreads();
    for (int off = 1; off < 256; off <<= 1) {
        unsigned int v = (t >= off) ? ls[t - off] : 0u;
        __syncthreads();
        ls[t] += v;
        __syncthreads();
    }
    unsigned int run = ls[t] - s;  // exclusive prefix
    for (int k = 0; k < 32; k++) {
        basearr[t * 32 + k] = run;
        fcursor[t * 32 + k] = run;
        run += local[k];
    }
    if (t == 255) basearr[NBUCK] = run;
}

// pass 2: within each coarse region, scatter into 128 fine buckets (LDS grouping)
__global__ __launch_bounds__(256) void pass2_kernel(const uint32_t* __restrict__ barr1,
                                                    const unsigned int* __restrict__ ccursor,
                                                    unsigned int* __restrict__ fcursor,
                                                    uint32_t* __restrict__ barr2) {
    __shared__ uint32_t grp[4096];
    __shared__ unsigned char grpb[4096];
    __shared__ unsigned int cnt[128], pref[128], curs[128], rbase[128];
    uint32_t tid = threadIdx.x;
    uint32_t reg = blockIdx.y;
    uint32_t lo = reg * REG, hi = ccursor[reg];
    for (uint32_t start = lo + blockIdx.x * 4096; start < hi; start += gridDim.x * 4096) {
        uint32_t n = min(4096u, hi - start);
        if (tid < 128) cnt[tid] = 0;
        __syncthreads();
        for (uint32_t l = tid; l < n; l += 256)
            atomicAdd(&cnt[(barr1[start + l] >> 18) & 127u], 1u);
        __syncthreads();
        if (tid == 0) {
            unsigned int run = 0;
            for (int b = 0; b < 128; b++) { pref[b] = run; curs[b] = run; run += cnt[b]; }
        }
        __syncthreads();
        if (tid < 128 && cnt[tid]) rbase[tid] = atomicAdd(&fcursor[reg * 128 + tid], cnt[tid]);
        for (uint32_t l = tid; l < n; l += 256) {
            uint32_t v = barr1[start + l];
            uint32_t b = (v >> 18) & 127u;
            unsigned int p = atomicAdd(&curs[b], 1u);
            grp[p] = v; grpb[p] = (unsigned char)b;
        }
        __syncthreads();
        for (uint32_t l = tid; l < n; l += 256) {
            uint32_t b = grpb[l];
            barr2[rbase[b] + (l - pref[b])] = grp[l];
        }
        __syncthreads();
    }
}

// ---------- per-bucket O(n) MSD counting sort (128 sub-bins, bits 17:11) ----------
__global__ __launch_bounds__(256) void bucket_sort_kernel(const uint32_t* __restrict__ barr,
                                                          const unsigned int* __restrict__ basearr,
                                                          uint32_t* __restrict__ h1, uint32_t* __restrict__ h2) {
    __shared__ uint32_t ord[4096];
    __shared__ unsigned int cnt[128], pref[128], curs[128];
    uint32_t b  = blockIdx.x;
    uint32_t lo = basearr[b], hi = basearr[b + 1];
    uint32_t n  = hi - lo;
    if (n == 0) return;
    if (n > 4096) n = 4096;   // unreachable for this distribution
    uint32_t tid = threadIdx.x;
    if (tid < 128) cnt[tid] = 0;
    __syncthreads();
    for (uint32_t i = tid; i < n; i += 256)
        atomicAdd(&cnt[(barr[lo + i] >> 11) & 127u], 1u);
    __syncthreads();
    if (tid == 0) {
        unsigned int run = 0;
        for (int d = 0; d < 128; d++) { pref[d] = run; curs[d] = run; run += cnt[d]; }
    }
    __syncthreads();
    for (uint32_t i = tid; i < n; i += 256) {
        uint32_t v = barr[lo + i];
        uint32_t d = (v >> 11) & 127u;
        unsigned int p = atomicAdd(&curs[d], 1u);
        ord[p] = v;
    }
    __syncthreads();
    for (uint32_t p = tid; p < n; p += 256) {
        uint32_t v = ord[p];
        uint32_t d = (v >> 11) & 127u;
        uint32_t l0 = pref[d], l1 = l0 + cnt[d];
        uint32_t r = 0;
        for (uint32_t qq = l0; qq < l1; qq++) {
            uint32_t u = ord[qq];
            r += (u < v) || (u == v && qq < p);
        }
        uint32_t gp = lo + l0 + r;
        if (gp & 1) h2[gp >> 1] = v; else h1[gp >> 1] = v;
    }
}

// ---------- bit-reversal permute: dst[i] = src[rev21(i)], tiled ----------
struct SrcPtrs { const uint32_t* p[8]; };

__global__ void bitrev_kernel(SrcPtrs srcs, uint32_t* __restrict__ dst) {
    __shared__ uint32_t tile[64 * 65];
    uint32_t poly = blockIdx.y;
    const uint32_t* src = srcs.p[poly];
    uint32_t* out = dst + (size_t)poly * NN;
    uint32_t m  = blockIdx.x;                 // 9-bit middle
    uint32_t rm = __brev(m) >> 23;            // rev9
    for (uint32_t l = threadIdx.x; l < 4096; l += blockDim.x) {
        uint32_t u = l >> 6, v = l & 63;
        tile[u * 65 + v] = src[(u << 15) | (rm << 6) | v];
    }
    __syncthreads();
    for (uint32_t l = threadIdx.x; l < 4096; l += blockDim.x) {
        uint32_t a = l >> 6, b = l & 63;
        uint32_t ra = __brev(a) >> 26, rb = __brev(b) >> 26;  // rev6
        out[(a << 15) | (m << 6) | b] = tile[rb * 65 + ra];
    }
}

// ---------- NTT stages 1..12, radix-4 (6 rounds); uint4 global I/O; twiddles in LDS ----------
// w2j trick: W_{s+1}[j]*J = W_{s+1}[j+h]  -> wt[3h+j], no montmul.
__device__ __forceinline__ uint32_t padi(uint32_t i) { return i + (i >> 5); }

__global__ __launch_bounds__(256) void ntt_phase1_kernel(uint32_t* __restrict__ polys,
                                                         const uint32_t* __restrict__ WT1) {
    __shared__ uint32_t wt[4096];
    __shared__ uint32_t sd[4224];     // padded: i + (i>>5)
    uint32_t* x = polys + (size_t)blockIdx.y * NN + (size_t)blockIdx.x * 4096;
    #pragma unroll
    for (uint32_t m = 0; m < 4; m++) {
        uint32_t l = m * 1024 + threadIdx.x * 4;
        uint4 v = *reinterpret_cast<const uint4*>(&x[l]);
        uint4 w = *reinterpret_cast<const uint4*>(&WT1[l]);
        uint32_t p = padi(l);
        sd[p] = v.x; sd[p + 1] = v.y; sd[p + 2] = v.z; sd[p + 3] = v.w;
        *reinterpret_cast<uint4*>(&wt[l]) = w;
    }
    __syncthreads();
    #pragma unroll
    for (int t = 0; t < 6; t++) {
        uint32_t h = 1u << (2 * t);
        #pragma unroll
        for (uint32_t m = 0; m < 4; m++) {
            uint32_t q = threadIdx.x + (m << 8);     // unit 0..1023
            uint32_t j = q & (h - 1);
            uint32_t grp = q >> (2 * t);
            uint32_t i0 = (grp << (2 * t + 2)) + j;
            uint32_t w1  = wt[h + j];
            uint32_t w2  = wt[2 * h + j];
            uint32_t w2j = wt[3 * h + j];
            uint32_t p0 = padi(i0), p1 = padi(i0 + h), p2 = padi(i0 + 2 * h), p3 = padi(i0 + 3 * h);
            uint32_t a0 = sd[p0], a1 = sd[p1], a2 = sd[p2], a3 = sd[p3];
            uint32_t t1 = montmul(w1, a1), t3 = montmul(w1, a3);
            uint32_t b0 = addmod(a0, t1), b1 = submod(a0, t1);
            uint32_t b2 = addmod(a2, t3), b3 = submod(a2, t3);
            uint32_t u2 = montmul(w2, b2), u3 = montmul(w2j, b3);
            sd[p0] = addmod(b0, u2);
            sd[p2] = submod(b0, u2);
            sd[p1] = addmod(b1, u3);
            sd[p3] = submod(b1, u3);
        }
        __syncthreads();
    }
    #pragma unroll
    for (uint32_t m = 0; m < 4; m++) {
        uint32_t l = m * 1024 + threadIdx.x * 4;
        uint32_t p = padi(l);
        uint4 v;
        v.x = montmul(sd[p], NINV_M);
        v.y = montmul(sd[p + 1], NINV_M);
        v.z = montmul(sd[p + 2], NINV_M);
        v.w = montmul(sd[p + 3], NINV_M);
        *reinterpret_cast<uint4*>(&x[l]) = v;
    }
}

// ---------- NTT stages 13..21: 32-col x 512-row tile (64KB LDS, conflict-free);
//            uint4/float4 global I/O; radix-4 x4 + radix-2; fused commit; XCD remap ----------
__global__ __launch_bounds__(512) void ntt_phase2_kernel(uint32_t* __restrict__ polys,
                                                         const uint32_t* __restrict__ ROWT,
                                                         const uint32_t* __restrict__ CW,
                                                         const float* __restrict__ g,
                                                         double* __restrict__ partials) {
    __shared__ __align__(16) uint32_t sd[16384];    // [row:512][col:32] — 64 KB, banks ≡ col
    uint32_t b = blockIdx.x;              // 0..1023
    uint32_t xcd = b & 7u, k = b >> 3;    // k: 0..127
    uint32_t poly = k >> 4;               // 0..7
    uint32_t c0_idx = xcd * 16u + (k & 15u);   // 0..127
    uint32_t* x = polys + (size_t)poly * NN;
    uint32_t c0 = c0_idx * 32u;
    uint32_t tid = threadIdx.x;           // 0..511
    uint32_t c = tid & 31u;
    uint32_t rt = tid >> 5;               // 0..15
    uint32_t cg = tid & 7u;               // col group (4 cols)
    uint32_t r0 = tid >> 3;               // 0..63

    #pragma unroll
    for (uint32_t kk = 0; kk < 8; kk++) {
        uint32_t row = r0 + kk * 64;
        uint4 v = *reinterpret_cast<const uint4*>(&x[(row << 12) + c0 + 4 * cg]);
        *reinterpret_cast<uint4*>(&sd[row * 32 + 4 * cg]) = v;
    }
    uint32_t cw[9];
    #pragma unroll
    for (int s = 0; s < 9; s++) cw[s] = CW[s * 4096 + c0 + c];
    __syncthreads();

    #pragma unroll
    for (int s = 0; s < 8; s += 2) {
        uint32_t h = 1u << s;
        #pragma unroll
        for (uint32_t m = 0; m < 8; m++) {
            uint32_t u = (rt << 3) + m;          // radix-4 unit 0..127
            uint32_t kk = u & (h - 1);
            uint32_t grp = u >> s;
            uint32_t r = (grp << (s + 2)) + kk;
            uint32_t w1  = montmul(ROWT[h + kk], cw[s]);
            uint32_t w2  = montmul(ROWT[2 * h + kk], cw[s + 1]);
            uint32_t w2j = montmul(ROWT[3 * h + kk], cw[s + 1]);
            uint32_t i0 = (r << 5) + c;
            uint32_t i1 = ((r + h) << 5) + c;
            uint32_t i2 = ((r + 2 * h) << 5) + c;
            uint32_t i3 = ((r + 3 * h) << 5) + c;
            uint32_t a0 = sd[i0], a1 = sd[i1], a2 = sd[i2], a3 = sd[i3];
            uint32_t t1 = montmul(w1, a1), t3 = montmul(w1, a3);
            uint32_t b0 = addmod(a0, t1), b1 = submod(a0, t1);
            uint32_t b2 = addmod(a2, t3), b3 = submod(a2, t3);
            uint32_t u2 = montmul(w2, b2), u3 = montmul(w2j, b3);
            sd[i0] = addmod(b0, u2);
            sd[i2] = submod(b0, u2);
            sd[i1] = addmod(b1, u3);
            sd[i3] = submod(b1, u3);
        }
        __syncthreads();
    }
    #pragma unroll
    for (uint32_t m = 0; m < 16; m++) {
        uint32_t kk = (rt << 4) + m;       // 0..255
        uint32_t w = montmul(ROWT[256 + kk], cw[8]);
        uint32_t i0 = (kk << 5) + c, i1 = ((kk + 256) << 5) + c;
        uint32_t u = sd[i0];
        uint32_t v = montmul(sd[i1], w);
        sd[i0] = addmod(u, v);
        sd[i1] = submod(u, v);
    }
    __syncthreads();

    float* xf = (float*)x;
    const float invp = (float)(1.0 / 2013265921.0);
    double a0 = 0.0, a1 = 0.0, a2 = 0.0;
    #pragma unroll
    for (uint32_t kk = 0; kk < 8; kk++) {
        uint32_t row = r0 + kk * 64;
        uint32_t idx0 = (row << 12) + c0 + 4 * cg;
        uint32_t base = row * 32 + 4 * cg;
        float f0 = (float)sd[base], f1 = (float)sd[base + 1];
        float f2 = (float)sd[base + 2], f3 = (float)sd[base + 3];
        float4 fv = make_float4(f0, f1, f2, f3);
        *reinterpret_cast<float4*>(&xf[idx0]) = fv;
        const float4* gp = reinterpret_cast<const float4*>(&g[(size_t)idx0 * 3]);
        float4 g0 = gp[0], g1 = gp[1], g2 = gp[2];
        float s0 = f0 * invp, s1 = f1 * invp, s2 = f2 * invp, s3 = f3 * invp;
        a0 += (double)(s0 * g0.x) + (double)(s1 * g0.w) + (double)(s2 * g1.z) + (double)(s3 * g2.y);
        a1 += (double)(s0 * g0.y) + (double)(s1 * g1.x) + (double)(s2 * g1.w) + (double)(s3 * g2.z);
        a2 += (double)(s0 * g0.z) + (double)(s1 * g1.y) + (double)(s2 * g2.x) + (double)(s3 * g2.w);
    }
    __syncthreads();
    double* red = (double*)sd;        // data dead — reuse as f64 reduction buffer
    double v3[3] = {a0, a1, a2};
    #pragma unroll
    for (int kq = 0; kq < 3; kq++) {
        red[tid] = v3[kq];
        __syncthreads();
        for (int off = 256; off > 0; off >>= 1) {
            if (tid < off) red[tid] += red[tid + off];
            __syncthreads();
        }
        if (tid == 0) partials[((size_t)poly * 128 + c0_idx) * 3 + kq] = red[0];
        __syncthreads();
    }
}

// ---------- final commit reduce: 8 polys x 128 blocks x 3 comps -> 24 floats ----------
__global__ void reduce_commits_kernel(const double* __restrict__ partials, float* __restrict__ outf) {
    __shared__ double red[256];
    int t = threadIdx.x;
    for (int k = 0; k < 24; k++) {
        int p = k / 3, cc = k % 3;
        red[t] = (t < 128) ? partials[((size_t)p * 128 + t) * 3 + cc] : 0.0;
        __syncthreads();
        for (int off = 128; off > 0; off >>= 1) {
            if (t < off) red[t] += red[t + off];
            __syncthreads();
        }
        if (t == 0) outf[k] = (float)red[0];
        __syncthreads();
    }
}

extern "C" void kernel_launch(void* const* d_in, const int* in_sizes, int n_in,
                              void* d_out, int out_size, void* d_ws, size_t ws_size,
                              hipStream_t stream) {
    const int* wl = (const int*)d_in[0];
    const int* wr = (const int*)d_in[1];
    const int* wo = (const int*)d_in[2];
    const int* w4 = (const int*)d_in[3];
    const int* t1 = (const int*)d_in[4];
    const int* t2 = (const int*)d_in[5];
    const int* t3 = (const int*)d_in[6];
    const int* t4 = (const int*)d_in[7];
    const int* q  = (const int*)d_in[8];
    const float* g = (const float*)d_in[9];
    const int* zp = (const int*)d_in[10];

    char* ws = (char*)d_ws;
    // compact twiddle tables
    uint32_t* WT1  = (uint32_t*)(ws);                         // 16 KB
    uint32_t* ROWT = (uint32_t*)(ws + (64u  << 10));          // 2 KB
    uint32_t* CW   = (uint32_t*)(ws + (128u << 10));          // 144 KB
    uint32_t* tcomp  = (uint32_t*)(ws + (8ull  << 20));       // 8 MB
    uint32_t* fcomp  = (uint32_t*)(ws + (16ull << 20));       // 8 MB
    uint32_t* h1     = (uint32_t*)(ws + (24ull << 20));       // 8 MB
    uint32_t* h2     = (uint32_t*)(ws + (32ull << 20));       // 8 MB
    // small buffers at 64 KiB-aligned offsets
    unsigned int* hist    = (unsigned int*)(ws + (40ull << 20));                  // 32 KB
    unsigned int* basearr = (unsigned int*)(ws + (40ull << 20) + (64u  << 10));   // 32 KB+4
    unsigned int* fcursor = (unsigned int*)(ws + (40ull << 20) + (128u << 10));   // 32 KB
    unsigned int* ccursor = (unsigned int*)(ws + (40ull << 20) + (232u << 10));   // 256 B
    double*       partials = (double*)    (ws + (40ull << 20) + (256u << 10));    // 24 KB (8-aligned)

    float* outf = (float*)d_out;
    uint32_t* outpolys = (uint32_t*)outf + 24;                      // 8*N, final floats (16B-aligned)
    uint32_t* barr1 = (uint32_t*)outf + 1024;                       // 64*REG u32 = 18.9 MB (pre-NTT scratch)
    uint32_t* barr2 = (uint32_t*)outf + 1024 + (5u << 20);          // 16 MB compact (pre-NTT scratch)

    hipMemsetAsync(hist, 0, NBUCK * sizeof(unsigned int), stream);

    twiddle_all_kernel<<<144, 256, 0, stream>>>(WT1, ROWT, CW);
    init_cursor_kernel<<<1, 64, 0, stream>>>(ccursor);

    compress_scatter_kernel<<<1024, 256, 0, stream>>>(wl, wr, wo, w4, t1, t2, t3, t4, q, zp,
                                                      tcomp, fcomp, ccursor, barr1);
    fine_hist_kernel<<<dim3(16, 64), 256, 0, stream>>>(barr1, ccursor, hist);
    scan_kernel<<<1, 256, 0, stream>>>(hist, basearr, fcursor);
    pass2_kernel<<<dim3(16, 64), 256, 0, stream>>>(barr1, ccursor, fcursor, barr2);
    bucket_sort_kernel<<<NBUCK, 256, 0, stream>>>(barr2, basearr, h1, h2);

    SrcPtrs sp;
    sp.p[0] = (const uint32_t*)wl;
    sp.p[1] = (const uint32_t*)wr;
    sp.p[2] = (const uint32_t*)wo;
    sp.p[3] = (const uint32_t*)w4;
    sp.p[4] = tcomp;
    sp.p[5] = fcomp;
    sp.p[6] = h1;
    sp.p[7] = h2;
    bitrev_kernel<<<dim3(512, 8), 256, 0, stream>>>(sp, outpolys);
    ntt_phase1_kernel<<<dim3(512, 8), 256, 0, stream>>>(outpolys, WT1);
    ntt_phase2_kernel<<<1024, 512, 0, stream>>>(outpolys, ROWT, CW, g, partials);

    reduce_commits_kernel<<<1, 256, 0, stream>>>(partials, outf);
}

// Round 17
// 265.227 us; speedup vs baseline: 1.2822x; 1.0437x over previous
//
#include <hip/hip_runtime.h>
#include <stdint.h>

#define PRIME 2013265921u
#define LOGN 21
#define NN (1u << LOGN)   // 2097152
#define REG 73728u        // padded coarse-region size: 2NN/60 (~69906) + 14.6 sigma
#define FREG 768u         // padded fine-region size: 512 + 11.3 sigma

// ---------- compile-time modular helpers ----------
constexpr uint32_t cpow(uint64_t b, uint64_t e) {
    uint64_t r = 1;
    b %= PRIME;
    while (e) {
        if (e & 1ull) r = r * b % PRIME;
        b = b * b % PRIME;
        e >>= 1;
    }
    return (uint32_t)r;
}
constexpr uint32_t cpinv() {           // PRIME^{-1} mod 2^32 (Newton)
    uint32_t inv = 1;
    for (int i = 0; i < 6; i++) inv *= 2u - PRIME * inv;
    return inv;
}
constexpr uint32_t NPRIME   = (uint32_t)(0u - cpinv());            // -P^{-1} mod 2^32
constexpr uint32_t RMODP    = (uint32_t)((1ull << 32) % PRIME);    // Mont(1)
constexpr uint32_t ROOT     = cpow(31u, (PRIME - 1) / NN);
constexpr uint32_t IROOT    = cpow(ROOT, PRIME - 2);
constexpr uint32_t NINV     = cpow(NN, PRIME - 2);
constexpr uint32_t NINV_M   = (uint32_t)((((uint64_t)NINV) << 32) % PRIME);  // Mont(N^-1)

// ---------- modular arithmetic ----------
__device__ __forceinline__ uint32_t addmod(uint32_t a, uint32_t b) {
    uint32_t s = a + b; return (s >= PRIME) ? s - PRIME : s;
}
__device__ __forceinline__ uint32_t submod(uint32_t a, uint32_t b) {
    return (a >= b) ? (a - b) : (a + PRIME - b);
}
__device__ __forceinline__ uint32_t mulmod(uint32_t a, uint32_t b) {
    return (uint32_t)(((uint64_t)a * (uint64_t)b) % PRIME);
}
// Montgomery: montmul(a_normal, Mont(b)) = a*b mod P; montmul(Mont(a),Mont(b)) = Mont(ab)
__device__ __forceinline__ uint32_t montmul(uint32_t a, uint32_t b) {
    uint64_t t = (uint64_t)a * b;
    uint32_t m = (uint32_t)t * NPRIME;
    uint32_t u = (uint32_t)((t + (uint64_t)m * PRIME) >> 32);
    return (u >= PRIME) ? u - PRIME : u;
}
__device__ uint32_t powmod(uint32_t b, uint32_t e) {
    uint32_t r = 1u;
    while (e) {
        if (e & 1u) r = mulmod(r, b);
        b = mulmod(b, b);
        e >>= 1;
    }
    return r;
}
__device__ __forceinline__ uint32_t tomont(uint32_t x) {
    return (uint32_t)((((uint64_t)x) << 32) % PRIME);
}

// ---------- twiddle tables (single dispatch, direct powmod) ----------
__global__ void twiddle_all_kernel(uint32_t* __restrict__ WT1, uint32_t* __restrict__ ROWT,
                                   uint32_t* __restrict__ CW) {
    uint32_t i = blockIdx.x * blockDim.x + threadIdx.x;   // < 36864
    if (i < 4096) {
        if (i == 0) WT1[0] = RMODP;
        else {
            uint32_t s = 31u - __clz(i);
            uint32_t j = i ^ (1u << s);
            WT1[i] = tomont(powmod(IROOT, j << (20u - s)));
        }
    }
    if (i < 512) {
        if (i == 0) ROWT[0] = RMODP;
        else {
            uint32_t t = 31u - __clz(i);
            ROWT[i] = tomont(powmod(IROOT, (i - (1u << t)) << (20u - t)));
        }
    }
    if (i < 36864) {
        uint32_t s = i >> 12, j = i & 4095u;
        CW[i] = tomont(powmod(IROOT, j << (8u - s)));
    }
}

// ---------- cursor init: coarse region b at b*REG; fine region b at b*FREG ----------
__global__ void init_cursor_kernel(unsigned int* __restrict__ ccursor,
                                   unsigned int* __restrict__ fcursor) {
    uint32_t i = blockIdx.x * blockDim.x + threadIdx.x;
    if (i < 8192) fcursor[i] = i * FREG;
    if (i < 64) ccursor[i] = i * REG;
}

// ---------- FUSED compress + coarse scatter (static padded regions, LDS grouping) ----------
__global__ __launch_bounds__(256) void compress_scatter_kernel(
        const int* __restrict__ wl, const int* __restrict__ wr,
        const int* __restrict__ wo, const int* __restrict__ w4,
        const int* __restrict__ t1, const int* __restrict__ t2,
        const int* __restrict__ t3, const int* __restrict__ t4,
        const int* __restrict__ q,  const int* __restrict__ zp,
        uint32_t* __restrict__ tcomp, uint32_t* __restrict__ fcomp,
        unsigned int* __restrict__ ccursor, uint32_t* __restrict__ barr1) {
    __shared__ uint32_t grp[4096];
    __shared__ unsigned char grpb[4096];
    __shared__ unsigned int cnt[64], pref[64], curs[64], rbase[64];
    uint32_t tid = threadIdx.x;
    uint32_t i0 = blockIdx.x * 2048u + tid * 8u;    // grid 1024 covers NN exactly
    if (tid < 64) cnt[tid] = 0;
    __syncthreads();

    uint32_t z1 = ((uint32_t)zp[0]) % PRIME;
    uint32_t z2 = mulmod(z1, z1);
    uint32_t z3 = mulmod(z2, z1);
    uint32_t tv[8], fv[8];
    #pragma unroll
    for (int h = 0; h < 2; h++) {
        uint32_t ib = i0 + (uint32_t)h * 4u;
        int4 a1 = *reinterpret_cast<const int4*>(&t1[ib]);
        int4 a2 = *reinterpret_cast<const int4*>(&t2[ib]);
        int4 a3 = *reinterpret_cast<const int4*>(&t3[ib]);
        int4 a4 = *reinterpret_cast<const int4*>(&t4[ib]);
        int4 b1 = *reinterpret_cast<const int4*>(&wl[ib]);
        int4 b2 = *reinterpret_cast<const int4*>(&wr[ib]);
        int4 b3 = *reinterpret_cast<const int4*>(&wo[ib]);
        int4 b4 = *reinterpret_cast<const int4*>(&w4[ib]);
        int4 qq = *reinterpret_cast<const int4*>(&q[ib]);
        int av1[4] = {a1.x, a1.y, a1.z, a1.w};
        int av2[4] = {a2.x, a2.y, a2.z, a2.w};
        int av3[4] = {a3.x, a3.y, a3.z, a3.w};
        int av4[4] = {a4.x, a4.y, a4.z, a4.w};
        int bv1[4] = {b1.x, b1.y, b1.z, b1.w};
        int bv2[4] = {b2.x, b2.y, b2.z, b2.w};
        int bv3[4] = {b3.x, b3.y, b3.z, b3.w};
        int bv4[4] = {b4.x, b4.y, b4.z, b4.w};
        int qv[4]  = {qq.x, qq.y, qq.z, qq.w};
        #pragma unroll
        for (int j = 0; j < 4; j++) {
            uint32_t t = addmod(addmod((uint32_t)av1[j], mulmod((uint32_t)av2[j], z1)),
                                addmod(mulmod((uint32_t)av3[j], z2), mulmod((uint32_t)av4[j], z3)));
            uint32_t w = addmod(addmod((uint32_t)bv1[j], mulmod((uint32_t)bv2[j], z1)),
                                addmod(mulmod((uint32_t)bv3[j], z2), mulmod((uint32_t)bv4[j], z3)));
            tv[h * 4 + j] = t;
            fv[h * 4 + j] = (qv[j] != 0) ? w : t;
        }
    }
    // store compressed streams (needed later as NTT inputs)
    *reinterpret_cast<uint4*>(&tcomp[i0])     = make_uint4(tv[0], tv[1], tv[2], tv[3]);
    *reinterpret_cast<uint4*>(&tcomp[i0 + 4]) = make_uint4(tv[4], tv[5], tv[6], tv[7]);
    *reinterpret_cast<uint4*>(&fcomp[i0])     = make_uint4(fv[0], fv[1], fv[2], fv[3]);
    *reinterpret_cast<uint4*>(&fcomp[i0 + 4]) = make_uint4(fv[4], fv[5], fv[6], fv[7]);

    // block-local coarse histogram over the 4096 values (2048 t + 2048 f)
    #pragma unroll
    for (int j = 0; j < 8; j++) {
        atomicAdd(&cnt[tv[j] >> 25], 1u);
        atomicAdd(&cnt[fv[j] >> 25], 1u);
    }
    __syncthreads();
    if (tid == 0) {
        unsigned int run = 0;
        for (int b = 0; b < 64; b++) { pref[b] = run; curs[b] = run; run += cnt[b]; }
    }
    __syncthreads();
    if (tid < 64 && cnt[tid]) rbase[tid] = atomicAdd(&ccursor[tid], cnt[tid]);
    // group into LDS by coarse bucket
    #pragma unroll
    for (int j = 0; j < 8; j++) {
        uint32_t v = tv[j];
        uint32_t b = v >> 25;
        unsigned int p = atomicAdd(&curs[b], 1u);
        grp[p] = v; grpb[p] = (unsigned char)b;
    }
    #pragma unroll
    for (int j = 0; j < 8; j++) {
        uint32_t v = fv[j];
        uint32_t b = v >> 25;
        unsigned int p = atomicAdd(&curs[b], 1u);
        grp[p] = v; grpb[p] = (unsigned char)b;
    }
    __syncthreads();
    // coalesced run writes into padded coarse regions
    for (uint32_t l = tid; l < 4096; l += 256) {
        uint32_t b = grpb[l];
        barr1[rbase[b] + (l - pref[b])] = grp[l];
    }
}

// ---------- sort ----------
#define NBUCK 8192

// pass 2: coarse region -> padded fine regions (static bases, no histogram needed)
__global__ __launch_bounds__(256) void pass2_kernel(const uint32_t* __restrict__ barr1,
                                                    const unsigned int* __restrict__ ccursor,
                                                    unsigned int* __restrict__ fcursor,
                                                    uint32_t* __restrict__ barr2) {
    __shared__ uint32_t grp[4096];
    __shared__ unsigned char grpb[4096];
    __shared__ unsigned int cnt[128], pref[128], curs[128], rbase[128];
    uint32_t tid = threadIdx.x;
    uint32_t reg = blockIdx.y;
    uint32_t lo = reg * REG, hi = ccursor[reg];
    for (uint32_t start = lo + blockIdx.x * 4096; start < hi; start += gridDim.x * 4096) {
        uint32_t n = min(4096u, hi - start);
        if (tid < 128) cnt[tid] = 0;
        __syncthreads();
        for (uint32_t l = tid; l < n; l += 256)
            atomicAdd(&cnt[(barr1[start + l] >> 18) & 127u], 1u);
        __syncthreads();
        if (tid == 0) {
            unsigned int run = 0;
            for (int b = 0; b < 128; b++) { pref[b] = run; curs[b] = run; run += cnt[b]; }
        }
        __syncthreads();
        if (tid < 128 && cnt[tid]) rbase[tid] = atomicAdd(&fcursor[reg * 128 + tid], cnt[tid]);
        for (uint32_t l = tid; l < n; l += 256) {
            uint32_t v = barr1[start + l];
            uint32_t b = (v >> 18) & 127u;
            unsigned int p = atomicAdd(&curs[b], 1u);
            grp[p] = v; grpb[p] = (unsigned char)b;
        }
        __syncthreads();
        for (uint32_t l = tid; l < n; l += 256) {
            uint32_t b = grpb[l];
            barr2[rbase[b] + (l - pref[b])] = grp[l];
        }
        __syncthreads();
    }
}

// scan AFTER pass2: counts from final fine cursors -> compact output offsets
__global__ void scan_kernel(const unsigned int* __restrict__ fcursor,
                            unsigned int* __restrict__ basearr) {
    __shared__ unsigned int ls[256];
    int t = threadIdx.x;
    unsigned int local[32];
    unsigned int s = 0;
    for (int k = 0; k < 32; k++) {
        uint32_t b = t * 32 + k;
        local[k] = fcursor[b] - b * FREG;
        s += local[k];
    }
    ls[t] = s;
    __syncthreads();
    for (int off = 1; off < 256; off <<= 1) {
        unsigned int v = (t >= off) ? ls[t - off] : 0u;
        __syncthreads();
        ls[t] += v;
        __syncthreads();
    }
    unsigned int run = ls[t] - s;  // exclusive prefix
    for (int k = 0; k < 32; k++) {
        basearr[t * 32 + k] = run;
        run += local[k];
    }
    if (t == 255) basearr[NBUCK] = run;
}

// ---------- per-bucket O(n) MSD counting sort (128 sub-bins, bits 17:11) ----------
// reads padded fine region [b*FREG, b*FREG+n); writes compact positions basearr[b]+rank
__global__ __launch_bounds__(256) void bucket_sort_kernel(const uint32_t* __restrict__ barr,
                                                          const unsigned int* __restrict__ basearr,
                                                          uint32_t* __restrict__ h1, uint32_t* __restrict__ h2) {
    __shared__ uint32_t ord[1024];
    __shared__ unsigned int cnt[128], pref[128], curs[128];
    uint32_t b  = blockIdx.x;
    uint32_t obase = basearr[b];
    uint32_t n = basearr[b + 1] - obase;
    if (n == 0) return;
    if (n > 1024) n = 1024;   // unreachable (fine bucket ~512 +- 22)
    uint32_t lo = b * FREG;
    uint32_t tid = threadIdx.x;
    if (tid < 128) cnt[tid] = 0;
    __syncthreads();
    for (uint32_t i = tid; i < n; i += 256)
        atomicAdd(&cnt[(barr[lo + i] >> 11) & 127u], 1u);
    __syncthreads();
    if (tid == 0) {
        unsigned int run = 0;
        for (int d = 0; d < 128; d++) { pref[d] = run; curs[d] = run; run += cnt[d]; }
    }
    __syncthreads();
    for (uint32_t i = tid; i < n; i += 256) {
        uint32_t v = barr[lo + i];
        uint32_t d = (v >> 11) & 127u;
        unsigned int p = atomicAdd(&curs[d], 1u);
        ord[p] = v;
    }
    __syncthreads();
    for (uint32_t p = tid; p < n; p += 256) {
        uint32_t v = ord[p];
        uint32_t d = (v >> 11) & 127u;
        uint32_t l0 = pref[d], l1 = l0 + cnt[d];
        uint32_t r = 0;
        for (uint32_t qq = l0; qq < l1; qq++) {
            uint32_t u = ord[qq];
            r += (u < v) || (u == v && qq < p);
        }
        uint32_t gp = obase + l0 + r;
        if (gp & 1) h2[gp >> 1] = v; else h1[gp >> 1] = v;
    }
}

// ---------- bit-reversal permute: dst[i] = src[rev21(i)], tiled ----------
struct SrcPtrs { const uint32_t* p[8]; };

__global__ void bitrev_kernel(SrcPtrs srcs, uint32_t* __restrict__ dst) {
    __shared__ uint32_t tile[64 * 65];
    uint32_t poly = blockIdx.y;
    const uint32_t* src = srcs.p[poly];
    uint32_t* out = dst + (size_t)poly * NN;
    uint32_t m  = blockIdx.x;                 // 9-bit middle
    uint32_t rm = __brev(m) >> 23;            // rev9
    for (uint32_t l = threadIdx.x; l < 4096; l += blockDim.x) {
        uint32_t u = l >> 6, v = l & 63;
        tile[u * 65 + v] = src[(u << 15) | (rm << 6) | v];
    }
    __syncthreads();
    for (uint32_t l = threadIdx.x; l < 4096; l += blockDim.x) {
        uint32_t a = l >> 6, b = l & 63;
        uint32_t ra = __brev(a) >> 26, rb = __brev(b) >> 26;  // rev6
        out[(a << 15) | (m << 6) | b] = tile[rb * 65 + ra];
    }
}

// ---------- NTT stages 1..12, radix-4 (6 rounds); uint4 global I/O; twiddles in LDS ----------
// w2j trick: W_{s+1}[j]*J = W_{s+1}[j+h]  -> wt[3h+j], no montmul.
__device__ __forceinline__ uint32_t padi(uint32_t i) { return i + (i >> 5); }

__global__ __launch_bounds__(256) void ntt_phase1_kernel(uint32_t* __restrict__ polys,
                                                         const uint32_t* __restrict__ WT1) {
    __shared__ uint32_t wt[4096];
    __shared__ uint32_t sd[4224];     // padded: i + (i>>5)
    uint32_t* x = polys + (size_t)blockIdx.y * NN + (size_t)blockIdx.x * 4096;
    #pragma unroll
    for (uint32_t m = 0; m < 4; m++) {
        uint32_t l = m * 1024 + threadIdx.x * 4;
        uint4 v = *reinterpret_cast<const uint4*>(&x[l]);
        uint4 w = *reinterpret_cast<const uint4*>(&WT1[l]);
        uint32_t p = padi(l);
        sd[p] = v.x; sd[p + 1] = v.y; sd[p + 2] = v.z; sd[p + 3] = v.w;
        *reinterpret_cast<uint4*>(&wt[l]) = w;
    }
    __syncthreads();
    #pragma unroll
    for (int t = 0; t < 6; t++) {
        uint32_t h = 1u << (2 * t);
        #pragma unroll
        for (uint32_t m = 0; m < 4; m++) {
            uint32_t q = threadIdx.x + (m << 8);     // unit 0..1023
            uint32_t j = q & (h - 1);
            uint32_t grp = q >> (2 * t);
            uint32_t i0 = (grp << (2 * t + 2)) + j;
            uint32_t w1  = wt[h + j];
            uint32_t w2  = wt[2 * h + j];
            uint32_t w2j = wt[3 * h + j];
            uint32_t p0 = padi(i0), p1 = padi(i0 + h), p2 = padi(i0 + 2 * h), p3 = padi(i0 + 3 * h);
            uint32_t a0 = sd[p0], a1 = sd[p1], a2 = sd[p2], a3 = sd[p3];
            uint32_t t1 = montmul(w1, a1), t3 = montmul(w1, a3);
            uint32_t b0 = addmod(a0, t1), b1 = submod(a0, t1);
            uint32_t b2 = addmod(a2, t3), b3 = submod(a2, t3);
            uint32_t u2 = montmul(w2, b2), u3 = montmul(w2j, b3);
            sd[p0] = addmod(b0, u2);
            sd[p2] = submod(b0, u2);
            sd[p1] = addmod(b1, u3);
            sd[p3] = submod(b1, u3);
        }
        __syncthreads();
    }
    #pragma unroll
    for (uint32_t m = 0; m < 4; m++) {
        uint32_t l = m * 1024 + threadIdx.x * 4;
        uint32_t p = padi(l);
        uint4 v;
        v.x = montmul(sd[p], NINV_M);
        v.y = montmul(sd[p + 1], NINV_M);
        v.z = montmul(sd[p + 2], NINV_M);
        v.w = montmul(sd[p + 3], NINV_M);
        *reinterpret_cast<uint4*>(&x[l]) = v;
    }
}

// ---------- NTT stages 13..21: 32-col x 512-row tile (64KB LDS, conflict-free);
//            uint4/float4 global I/O; radix-4 x4 + radix-2; fused commit; XCD remap ----------
__global__ __launch_bounds__(512) void ntt_phase2_kernel(uint32_t* __restrict__ polys,
                                                         const uint32_t* __restrict__ ROWT,
                                                         const uint32_t* __restrict__ CW,
                                                         const float* __restrict__ g,
                                                         double* __restrict__ partials) {
    __shared__ __align__(16) uint32_t sd[16384];    // [row:512][col:32] — 64 KB, banks ≡ col
    uint32_t b = blockIdx.x;              // 0..1023
    uint32_t xcd = b & 7u, k = b >> 3;    // k: 0..127
    uint32_t poly = k >> 4;               // 0..7
    uint32_t c0_idx = xcd * 16u + (k & 15u);   // 0..127
    uint32_t* x = polys + (size_t)poly * NN;
    uint32_t c0 = c0_idx * 32u;
    uint32_t tid = threadIdx.x;           // 0..511
    uint32_t c = tid & 31u;
    uint32_t rt = tid >> 5;               // 0..15
    uint32_t cg = tid & 7u;               // col group (4 cols)
    uint32_t r0 = tid >> 3;               // 0..63

    #pragma unroll
    for (uint32_t kk = 0; kk < 8; kk++) {
        uint32_t row = r0 + kk * 64;
        uint4 v = *reinterpret_cast<const uint4*>(&x[(row << 12) + c0 + 4 * cg]);
        *reinterpret_cast<uint4*>(&sd[row * 32 + 4 * cg]) = v;
    }
    uint32_t cw[9];
    #pragma unroll
    for (int s = 0; s < 9; s++) cw[s] = CW[s * 4096 + c0 + c];
    __syncthreads();

    #pragma unroll
    for (int s = 0; s < 8; s += 2) {
        uint32_t h = 1u << s;
        #pragma unroll
        for (uint32_t m = 0; m < 8; m++) {
            uint32_t u = (rt << 3) + m;          // radix-4 unit 0..127
            uint32_t kk = u & (h - 1);
            uint32_t grp = u >> s;
            uint32_t r = (grp << (s + 2)) + kk;
            uint32_t w1  = montmul(ROWT[h + kk], cw[s]);
            uint32_t w2  = montmul(ROWT[2 * h + kk], cw[s + 1]);
            uint32_t w2j = montmul(ROWT[3 * h + kk], cw[s + 1]);
            uint32_t i0 = (r << 5) + c;
            uint32_t i1 = ((r + h) << 5) + c;
            uint32_t i2 = ((r + 2 * h) << 5) + c;
            uint32_t i3 = ((r + 3 * h) << 5) + c;
            uint32_t a0 = sd[i0], a1 = sd[i1], a2 = sd[i2], a3 = sd[i3];
            uint32_t t1 = montmul(w1, a1), t3 = montmul(w1, a3);
            uint32_t b0 = addmod(a0, t1), b1 = submod(a0, t1);
            uint32_t b2 = addmod(a2, t3), b3 = submod(a2, t3);
            uint32_t u2 = montmul(w2, b2), u3 = montmul(w2j, b3);
            sd[i0] = addmod(b0, u2);
            sd[i2] = submod(b0, u2);
            sd[i1] = addmod(b1, u3);
            sd[i3] = submod(b1, u3);
        }
        __syncthreads();
    }
    #pragma unroll
    for (uint32_t m = 0; m < 16; m++) {
        uint32_t kk = (rt << 4) + m;       // 0..255
        uint32_t w = montmul(ROWT[256 + kk], cw[8]);
        uint32_t i0 = (kk << 5) + c, i1 = ((kk + 256) << 5) + c;
        uint32_t u = sd[i0];
        uint32_t v = montmul(sd[i1], w);
        sd[i0] = addmod(u, v);
        sd[i1] = submod(u, v);
    }
    __syncthreads();

    float* xf = (float*)x;
    const float invp = (float)(1.0 / 2013265921.0);
    double a0 = 0.0, a1 = 0.0, a2 = 0.0;
    #pragma unroll
    for (uint32_t kk = 0; kk < 8; kk++) {
        uint32_t row = r0 + kk * 64;
        uint32_t idx0 = (row << 12) + c0 + 4 * cg;
        uint32_t base = row * 32 + 4 * cg;
        float f0 = (float)sd[base], f1 = (float)sd[base + 1];
        float f2 = (float)sd[base + 2], f3 = (float)sd[base + 3];
        float4 fv = make_float4(f0, f1, f2, f3);
        *reinterpret_cast<float4*>(&xf[idx0]) = fv;
        const float4* gp = reinterpret_cast<const float4*>(&g[(size_t)idx0 * 3]);
        float4 g0 = gp[0], g1 = gp[1], g2 = gp[2];
        float s0 = f0 * invp, s1 = f1 * invp, s2 = f2 * invp, s3 = f3 * invp;
        a0 += (double)(s0 * g0.x) + (double)(s1 * g0.w) + (double)(s2 * g1.z) + (double)(s3 * g2.y);
        a1 += (double)(s0 * g0.y) + (double)(s1 * g1.x) + (double)(s2 * g1.w) + (double)(s3 * g2.z);
        a2 += (double)(s0 * g0.z) + (double)(s1 * g1.y) + (double)(s2 * g2.x) + (double)(s3 * g2.w);
    }
    __syncthreads();
    double* red = (double*)sd;        // data dead — reuse as f64 reduction buffer
    double v3[3] = {a0, a1, a2};
    #pragma unroll
    for (int kq = 0; kq < 3; kq++) {
        red[tid] = v3[kq];
        __syncthreads();
        for (int off = 256; off > 0; off >>= 1) {
            if (tid < off) red[tid] += red[tid + off];
            __syncthreads();
        }
        if (tid == 0) partials[((size_t)poly * 128 + c0_idx) * 3 + kq] = red[0];
        __syncthreads();
    }
}

// ---------- final commit reduce: 8 polys x 128 blocks x 3 comps -> 24 floats ----------
__global__ void reduce_commits_kernel(const double* __restrict__ partials, float* __restrict__ outf) {
    __shared__ double red[256];
    int t = threadIdx.x;
    for (int k = 0; k < 24; k++) {
        int p = k / 3, cc = k % 3;
        red[t] = (t < 128) ? partials[((size_t)p * 128 + t) * 3 + cc] : 0.0;
        __syncthreads();
        for (int off = 128; off > 0; off >>= 1) {
            if (t < off) red[t] += red[t + off];
            __syncthreads();
        }
        if (t == 0) outf[k] = (float)red[0];
        __syncthreads();
    }
}

extern "C" void kernel_launch(void* const* d_in, const int* in_sizes, int n_in,
                              void* d_out, int out_size, void* d_ws, size_t ws_size,
                              hipStream_t stream) {
    const int* wl = (const int*)d_in[0];
    const int* wr = (const int*)d_in[1];
    const int* wo = (const int*)d_in[2];
    const int* w4 = (const int*)d_in[3];
    const int* t1 = (const int*)d_in[4];
    const int* t2 = (const int*)d_in[5];
    const int* t3 = (const int*)d_in[6];
    const int* t4 = (const int*)d_in[7];
    const int* q  = (const int*)d_in[8];
    const float* g = (const float*)d_in[9];
    const int* zp = (const int*)d_in[10];

    char* ws = (char*)d_ws;
    // compact twiddle tables
    uint32_t* WT1  = (uint32_t*)(ws);                         // 16 KB
    uint32_t* ROWT = (uint32_t*)(ws + (64u  << 10));          // 2 KB
    uint32_t* CW   = (uint32_t*)(ws + (128u << 10));          // 144 KB
    uint32_t* tcomp  = (uint32_t*)(ws + (8ull  << 20));       // 8 MB
    uint32_t* fcomp  = (uint32_t*)(ws + (16ull << 20));       // 8 MB
    uint32_t* h1     = (uint32_t*)(ws + (24ull << 20));       // 8 MB
    uint32_t* h2     = (uint32_t*)(ws + (32ull << 20));       // 8 MB
    // small buffers at 64 KiB-aligned offsets
    unsigned int* basearr = (unsigned int*)(ws + (40ull << 20) + (64u  << 10));   // 32 KB+4
    unsigned int* fcursor = (unsigned int*)(ws + (40ull << 20) + (128u << 10));   // 32 KB
    unsigned int* ccursor = (unsigned int*)(ws + (40ull << 20) + (232u << 10));   // 256 B
    double*       partials = (double*)    (ws + (40ull << 20) + (256u << 10));    // 24 KB (8-aligned)

    float* outf = (float*)d_out;
    uint32_t* outpolys = (uint32_t*)outf + 24;                      // 8*N, final floats (16B-aligned)
    uint32_t* barr1 = (uint32_t*)outf + 1024;                       // 64*REG u32 = 18.9 MB (pre-NTT scratch)
    uint32_t* barr2 = (uint32_t*)outf + 1024 + (5u << 20);          // 8192*FREG u32 = 25.2 MB (pre-NTT scratch)

    twiddle_all_kernel<<<144, 256, 0, stream>>>(WT1, ROWT, CW);
    init_cursor_kernel<<<32, 256, 0, stream>>>(ccursor, fcursor);

    compress_scatter_kernel<<<1024, 256, 0, stream>>>(wl, wr, wo, w4, t1, t2, t3, t4, q, zp,
                                                      tcomp, fcomp, ccursor, barr1);
    pass2_kernel<<<dim3(16, 64), 256, 0, stream>>>(barr1, ccursor, fcursor, barr2);
    scan_kernel<<<1, 256, 0, stream>>>(fcursor, basearr);
    bucket_sort_kernel<<<NBUCK, 256, 0, stream>>>(barr2, basearr, h1, h2);

    SrcPtrs sp;
    sp.p[0] = (const uint32_t*)wl;
    sp.p[1] = (const uint32_t*)wr;
    sp.p[2] = (const uint32_t*)wo;
    sp.p[3] = (const uint32_t*)w4;
    sp.p[4] = tcomp;
    sp.p[5] = fcomp;
    sp.p[6] = h1;
    sp.p[7] = h2;
    bitrev_kernel<<<dim3(512, 8), 256, 0, stream>>>(sp, outpolys);
    ntt_phase1_kernel<<<dim3(512, 8), 256, 0, stream>>>(outpolys, WT1);
    ntt_phase2_kernel<<<1024, 512, 0, stream>>>(outpolys, ROWT, CW, g, partials);

    reduce_commits_kernel<<<1, 256, 0, stream>>>(partials, outf);
}